// Round 1
// baseline (751.351 us; speedup 1.0000x reference)
//
#include <hip/hip_runtime.h>
#include <cstdint>
#include <cstddef>

typedef unsigned short u16;
typedef __bf16 bf16x8 __attribute__((ext_vector_type(8)));
typedef unsigned short u16x8 __attribute__((ext_vector_type(8)));
typedef float f32x4 __attribute__((ext_vector_type(4)));

#define DIMN 768
#define BNROWS 16384
#define NH 12
#define HD 64
#define HID 3072
#define QKVN 2304

__device__ __forceinline__ u16 f2bf(float f) {
  unsigned u = __builtin_bit_cast(unsigned, f);
  u += 0x7fffu + ((u >> 16) & 1u);
  return (u16)(u >> 16);
}

__device__ __forceinline__ bf16x8 ld8(const u16* p) {
  u16x8 v = *reinterpret_cast<const u16x8*>(p);
  return __builtin_bit_cast(bf16x8, v);
}

__device__ __forceinline__ void gload16(const void* g, void* l) {
  __builtin_amdgcn_global_load_lds(
      (const __attribute__((address_space(1))) unsigned int*)g,
      (__attribute__((address_space(3))) unsigned int*)l, 16, 0, 0);
}

#define MFMA(a, b, c) __builtin_amdgcn_mfma_f32_16x16x32_bf16(a, b, c, 0, 0, 0)

// ---------------- weight transpose + cast: W[K,N] f32 -> Wt[N,K] bf16 ----------------
__global__ __launch_bounds__(256) void twb_k(const float* __restrict__ W,
                                             u16* __restrict__ Wt, int K, int N) {
  __shared__ float tile[32][33];
  const int n0 = blockIdx.x * 32, k0 = blockIdx.y * 32;
  const int tx = threadIdx.x & 31, ty = threadIdx.x >> 5;  // ty 0..7
#pragma unroll
  for (int i = 0; i < 4; i++)
    tile[ty + i * 8][tx] = W[(size_t)(k0 + ty + i * 8) * N + n0 + tx];
  __syncthreads();
#pragma unroll
  for (int i = 0; i < 4; i++)
    Wt[(size_t)(n0 + ty + i * 8) * K + k0 + tx] = f2bf(tile[tx][ty + i * 8]);
}

// ---------------- LayerNorm: fp32 row -> bf16 row (one wave per 768-row) ----------------
__global__ __launch_bounds__(256) void ln_k(const float* __restrict__ x,
                                            const float* __restrict__ g,
                                            const float* __restrict__ bta,
                                            u16* __restrict__ outp) {
  const int row = blockIdx.x * 4 + (threadIdx.x >> 6);
  const int lane = threadIdx.x & 63;
  const float4* xr = (const float4*)(x + (size_t)row * DIMN);
  float4 v[3];
  float s = 0.f, ss = 0.f;
#pragma unroll
  for (int c = 0; c < 3; c++) {
    v[c] = xr[c * 64 + lane];
    s += v[c].x + v[c].y + v[c].z + v[c].w;
    ss += v[c].x * v[c].x + v[c].y * v[c].y + v[c].z * v[c].z + v[c].w * v[c].w;
  }
#pragma unroll
  for (int off = 1; off < 64; off <<= 1) {
    s += __shfl_xor(s, off);
    ss += __shfl_xor(ss, off);
  }
  const float mu = s * (1.f / DIMN);
  const float var = ss * (1.f / DIMN) - mu * mu;
  const float rs = rsqrtf(var + 1e-5f);
  u16* orow = outp + (size_t)row * DIMN;
#pragma unroll
  for (int c = 0; c < 3; c++) {
    float4 gv = ((const float4*)g)[c * 64 + lane];
    float4 bv = ((const float4*)bta)[c * 64 + lane];
    ushort4 o;
    o.x = f2bf((v[c].x - mu) * rs * gv.x + bv.x);
    o.y = f2bf((v[c].y - mu) * rs * gv.y + bv.y);
    o.z = f2bf((v[c].z - mu) * rs * gv.z + bv.z);
    o.w = f2bf((v[c].w - mu) * rs * gv.w + bv.w);
    ((ushort4*)orow)[c * 64 + lane] = o;
  }
}

// ---------------- GEMM: C[M,N] = A[M,K]bf16 * Bt[N,K]bf16 + bias (+relu) (+resid) ----------------
template <int OUT_BF16, int RELU, int RESID>
__global__ __launch_bounds__(256) void gemm_k(const u16* __restrict__ A,
                                              const u16* __restrict__ Bt,
                                              const float* __restrict__ bias,
                                              const float* __restrict__ resid,
                                              void* __restrict__ Cout, int N, int K) {
  __shared__ u16 As[128 * 32];
  __shared__ u16 Bs[128 * 32];
  const int tid = threadIdx.x;
  const int m0 = blockIdx.x * 128;
  const int n0 = blockIdx.y * 128;
  const int lane = tid & 63, w = tid >> 6;
  const int wr = (w >> 1) * 64, wc = (w & 1) * 64;
  const int lhi = lane >> 4, llo = lane & 15;
  const int sr = tid >> 2, sc8 = (tid & 3) * 8;

  const u16* Ab = A + (size_t)(m0 + sr) * K + sc8;
  const u16* Bb = Bt + (size_t)(n0 + sr) * K + sc8;
  const size_t rstride = (size_t)64 * K;

  f32x4 acc[4][4] = {};

  for (int k0 = 0; k0 < K; k0 += 32) {
    __syncthreads();
    gload16(Ab + k0, (char*)As + tid * 16);
    gload16(Ab + rstride + k0, (char*)As + 4096 + tid * 16);
    gload16(Bb + k0, (char*)Bs + tid * 16);
    gload16(Bb + rstride + k0, (char*)Bs + 4096 + tid * 16);
    __syncthreads();
    bf16x8 af[4], bfr[4];
#pragma unroll
    for (int mi = 0; mi < 4; mi++) af[mi] = ld8(&As[(wr + mi * 16 + llo) * 32 + lhi * 8]);
#pragma unroll
    for (int ni = 0; ni < 4; ni++) bfr[ni] = ld8(&Bs[(wc + ni * 16 + llo) * 32 + lhi * 8]);
#pragma unroll
    for (int mi = 0; mi < 4; mi++)
#pragma unroll
      for (int ni = 0; ni < 4; ni++) acc[mi][ni] = MFMA(af[mi], bfr[ni], acc[mi][ni]);
  }

#pragma unroll
  for (int mi = 0; mi < 4; mi++)
#pragma unroll
    for (int ni = 0; ni < 4; ni++) {
      const int row = m0 + wr + mi * 16 + lhi * 4;
      const int col = n0 + wc + ni * 16 + llo;
      const float bsv = bias[col];
#pragma unroll
      for (int rr = 0; rr < 4; rr++) {
        float v = acc[mi][ni][rr] + bsv;
        if (RELU) v = fmaxf(v, 0.0f);
        const size_t idx = (size_t)(row + rr) * N + col;
        if (RESID) v += resid[idx];
        if (OUT_BF16)
          ((u16*)Cout)[idx] = f2bf(v);
        else
          ((float*)Cout)[idx] = v;
      }
    }
}

// ---------------- fused attention: qkv[B*N,2304]bf16 -> out[B*N,768]bf16 ----------------
__global__ __launch_bounds__(256) void attn_k(const u16* __restrict__ qkv,
                                              u16* __restrict__ outp) {
  __shared__ u16 Qs[64 * 64];
  __shared__ u16 Ks[64 * 64];
  __shared__ u16 Vt[64 * 64];  // Vt[d][kv]
  __shared__ u16 Ps[4][16 * 64];

  const int tid = threadIdx.x;
  const int qt = blockIdx.x;   // 0..15
  const int bh = blockIdx.y;   // 0..191
  const int b = bh / NH, h = bh % NH;
  const int lane = tid & 63, w = tid >> 6;
  const int lhi = lane >> 4, llo = lane & 15;
  const size_t rowb = (size_t)b * 1024;
  const float sscale = 0.03608439182435161f;  // 768^-0.5

  // stage Q tile [64 rows][64 d]
#pragma unroll
  for (int s = 0; s < 2; s++) {
    int cc = tid + s * 256;
    int r = cc >> 3, c8 = (cc & 7) * 8;
    gload16(&qkv[(rowb + qt * 64 + r) * QKVN + h * HD + c8], (char*)Qs + cc * 16);
  }

  float mrow[4], lrow[4];
  f32x4 oacc[4] = {};
#pragma unroll
  for (int r = 0; r < 4; r++) {
    mrow[r] = -1e30f;
    lrow[r] = 0.f;
  }

  for (int kt = 0; kt < 16; kt++) {
    __syncthreads();
#pragma unroll
    for (int s = 0; s < 2; s++) {
      int cc = tid + s * 256;
      int r = cc >> 3, c8 = (cc & 7) * 8;
      gload16(&qkv[(rowb + kt * 64 + r) * QKVN + DIMN + h * HD + c8], (char*)Ks + cc * 16);
      u16x8 vv = *reinterpret_cast<const u16x8*>(
          &qkv[(rowb + kt * 64 + r) * QKVN + 2 * DIMN + h * HD + c8]);
#pragma unroll
      for (int j = 0; j < 8; j++) Vt[(c8 + j) * 64 + r] = vv[j];
    }
    __syncthreads();

    // S = Q K^T  (wave w owns q-rows w*16..w*16+15, all 64 kv cols)
    f32x4 sacc[4] = {};
#pragma unroll
    for (int ks = 0; ks < 2; ks++) {
      bf16x8 qa = ld8(&Qs[(w * 16 + llo) * 64 + ks * 32 + lhi * 8]);
#pragma unroll
      for (int ni = 0; ni < 4; ni++) {
        bf16x8 kb = ld8(&Ks[(ni * 16 + llo) * 64 + ks * 32 + lhi * 8]);
        sacc[ni] = MFMA(qa, kb, sacc[ni]);
      }
    }

    // online softmax (rows lhi*4+r, wave-parallel reduce over llo)
#pragma unroll
    for (int r = 0; r < 4; r++) {
      float s0 = sacc[0][r] * sscale, s1 = sacc[1][r] * sscale;
      float s2 = sacc[2][r] * sscale, s3 = sacc[3][r] * sscale;
      float sm = fmaxf(fmaxf(s0, s1), fmaxf(s2, s3));
      sm = fmaxf(sm, __shfl_xor(sm, 1));
      sm = fmaxf(sm, __shfl_xor(sm, 2));
      sm = fmaxf(sm, __shfl_xor(sm, 4));
      sm = fmaxf(sm, __shfl_xor(sm, 8));
      float mnew = fmaxf(mrow[r], sm);
      float scale = __expf(mrow[r] - mnew);
      mrow[r] = mnew;
      float p0 = __expf(s0 - mnew), p1 = __expf(s1 - mnew);
      float p2 = __expf(s2 - mnew), p3 = __expf(s3 - mnew);
      float ps = p0 + p1 + p2 + p3;
      ps += __shfl_xor(ps, 1);
      ps += __shfl_xor(ps, 2);
      ps += __shfl_xor(ps, 4);
      ps += __shfl_xor(ps, 8);
      lrow[r] = lrow[r] * scale + ps;
#pragma unroll
      for (int ni = 0; ni < 4; ni++) oacc[ni][r] *= scale;
      const int pr = (lhi * 4 + r) * 64 + llo;
      Ps[w][pr] = f2bf(p0);
      Ps[w][pr + 16] = f2bf(p1);
      Ps[w][pr + 32] = f2bf(p2);
      Ps[w][pr + 48] = f2bf(p3);
    }
    __syncthreads();

    // O += P V
#pragma unroll
    for (int ks = 0; ks < 2; ks++) {
      bf16x8 pa = ld8(&Ps[w][llo * 64 + ks * 32 + lhi * 8]);
#pragma unroll
      for (int ni = 0; ni < 4; ni++) {
        bf16x8 vb = ld8(&Vt[(ni * 16 + llo) * 64 + ks * 32 + lhi * 8]);
        oacc[ni] = MFMA(pa, vb, oacc[ni]);
      }
    }
  }

#pragma unroll
  for (int ni = 0; ni < 4; ni++)
#pragma unroll
    for (int r = 0; r < 4; r++) {
      const size_t row = rowb + qt * 64 + w * 16 + lhi * 4 + r;
      outp[row * DIMN + h * HD + ni * 16 + llo] = f2bf(oacc[ni][r] / lrow[r]);
    }
}

extern "C" void kernel_launch(void* const* d_in, const int* in_sizes, int n_in,
                              void* d_out, int out_size, void* d_ws, size_t ws_size,
                              hipStream_t stream) {
  const float* x = (const float*)d_in[0];
  const float* Wqkv = (const float*)d_in[1];
  const float* bqkv = (const float*)d_in[2];
  const float* Wproj = (const float*)d_in[3];
  const float* bproj = (const float*)d_in[4];
  const float* g1 = (const float*)d_in[5];
  const float* b1 = (const float*)d_in[6];
  const float* g2 = (const float*)d_in[7];
  const float* b2 = (const float*)d_in[8];
  const float* W1 = (const float*)d_in[9];
  const float* bf1 = (const float*)d_in[10];
  const float* W2 = (const float*)d_in[11];
  const float* bf2 = (const float*)d_in[12];
  float* outp = (float*)d_out;

  char* p = (char*)d_ws;
  u16* WqkvT = (u16*)p; p += (size_t)QKVN * DIMN * 2;
  u16* WprojT = (u16*)p; p += (size_t)DIMN * DIMN * 2;
  u16* W1T = (u16*)p; p += (size_t)HID * DIMN * 2;
  u16* W2T = (u16*)p; p += (size_t)DIMN * HID * 2;
  u16* bufX = (u16*)p; p += (size_t)BNROWS * DIMN * 2;  // h1 / attn_out / h2
  u16* big = (u16*)p; p += (size_t)BNROWS * HID * 2;    // qkv then ff1

  // weight transposes (fp32 -> bf16, [K,N] -> [N,K])
  twb_k<<<dim3(QKVN / 32, DIMN / 32), 256, 0, stream>>>(Wqkv, WqkvT, DIMN, QKVN);
  twb_k<<<dim3(DIMN / 32, DIMN / 32), 256, 0, stream>>>(Wproj, WprojT, DIMN, DIMN);
  twb_k<<<dim3(HID / 32, DIMN / 32), 256, 0, stream>>>(W1, W1T, DIMN, HID);
  twb_k<<<dim3(DIMN / 32, HID / 32), 256, 0, stream>>>(W2, W2T, HID, DIMN);

  // LN1
  ln_k<<<BNROWS / 4, 256, 0, stream>>>(x, g1, b1, bufX);
  // QKV GEMM -> big (bf16)
  gemm_k<1, 0, 0><<<dim3(128, QKVN / 128), 256, 0, stream>>>(bufX, WqkvT, bqkv, nullptr,
                                                             big, QKVN, DIMN);
  // attention -> bufX (bf16)
  attn_k<<<dim3(16, 16 * NH), 256, 0, stream>>>(big, bufX);
  // proj GEMM + residual(x) -> d_out (fp32)
  gemm_k<0, 0, 1><<<dim3(128, DIMN / 128), 256, 0, stream>>>(bufX, WprojT, bproj, x, outp,
                                                             DIMN, DIMN);
  // LN2
  ln_k<<<BNROWS / 4, 256, 0, stream>>>(outp, g2, b2, bufX);
  // FF1 (relu) -> big (bf16)
  gemm_k<1, 1, 0><<<dim3(128, HID / 128), 256, 0, stream>>>(bufX, W1T, bf1, nullptr, big,
                                                            HID, DIMN);
  // FF2 + residual(d_out) -> d_out (fp32, in place)
  gemm_k<0, 0, 1><<<dim3(128, DIMN / 128), 256, 0, stream>>>(big, W2T, bf2, outp, outp,
                                                             DIMN, HID);
}

// Round 2
// 694.305 us; speedup vs baseline: 1.0822x; 1.0822x over previous
//
#include <hip/hip_runtime.h>
#include <cstdint>
#include <cstddef>

typedef unsigned short u16;
typedef __bf16 bf16x8 __attribute__((ext_vector_type(8)));
typedef unsigned short u16x8 __attribute__((ext_vector_type(8)));
typedef float f32x4 __attribute__((ext_vector_type(4)));

#define DIMN 768
#define BNROWS 16384
#define NH 12
#define HD 64
#define HID 3072
#define QKVN 2304

__device__ __forceinline__ u16 f2bf(float f) {
  unsigned u = __builtin_bit_cast(unsigned, f);
  u += 0x7fffu + ((u >> 16) & 1u);
  return (u16)(u >> 16);
}

__device__ __forceinline__ bf16x8 ld8(const u16* p) {
  u16x8 v = *reinterpret_cast<const u16x8*>(p);
  return __builtin_bit_cast(bf16x8, v);
}

__device__ __forceinline__ void gload16(const void* g, void* l) {
  __builtin_amdgcn_global_load_lds(
      (const __attribute__((address_space(1))) unsigned int*)g,
      (__attribute__((address_space(3))) unsigned int*)l, 16, 0, 0);
}

#define MFMA(a, b, c) __builtin_amdgcn_mfma_f32_16x16x32_bf16(a, b, c, 0, 0, 0)

// ---------------- weight transpose + cast: W[K,N] f32 -> Wt[N,K] bf16 ----------------
__global__ __launch_bounds__(256) void twb_k(const float* __restrict__ W,
                                             u16* __restrict__ Wt, int K, int N) {
  __shared__ float tile[32][33];
  const int n0 = blockIdx.x * 32, k0 = blockIdx.y * 32;
  const int tx = threadIdx.x & 31, ty = threadIdx.x >> 5;  // ty 0..7
#pragma unroll
  for (int i = 0; i < 4; i++)
    tile[ty + i * 8][tx] = W[(size_t)(k0 + ty + i * 8) * N + n0 + tx];
  __syncthreads();
#pragma unroll
  for (int i = 0; i < 4; i++)
    Wt[(size_t)(n0 + ty + i * 8) * K + k0 + tx] = f2bf(tile[tx][ty + i * 8]);
}

// ---------------- LayerNorm: fp32 row -> bf16 row (one wave per 768-row) ----------------
__global__ __launch_bounds__(256) void ln_k(const float* __restrict__ x,
                                            const float* __restrict__ g,
                                            const float* __restrict__ bta,
                                            u16* __restrict__ outp) {
  const int row = blockIdx.x * 4 + (threadIdx.x >> 6);
  const int lane = threadIdx.x & 63;
  const float4* xr = (const float4*)(x + (size_t)row * DIMN);
  float4 v[3];
  float s = 0.f, ss = 0.f;
#pragma unroll
  for (int c = 0; c < 3; c++) {
    v[c] = xr[c * 64 + lane];
    s += v[c].x + v[c].y + v[c].z + v[c].w;
    ss += v[c].x * v[c].x + v[c].y * v[c].y + v[c].z * v[c].z + v[c].w * v[c].w;
  }
#pragma unroll
  for (int off = 1; off < 64; off <<= 1) {
    s += __shfl_xor(s, off);
    ss += __shfl_xor(ss, off);
  }
  const float mu = s * (1.f / DIMN);
  const float var = ss * (1.f / DIMN) - mu * mu;
  const float rs = rsqrtf(var + 1e-5f);
  u16* orow = outp + (size_t)row * DIMN;
#pragma unroll
  for (int c = 0; c < 3; c++) {
    float4 gv = ((const float4*)g)[c * 64 + lane];
    float4 bv = ((const float4*)bta)[c * 64 + lane];
    ushort4 o;
    o.x = f2bf((v[c].x - mu) * rs * gv.x + bv.x);
    o.y = f2bf((v[c].y - mu) * rs * gv.y + bv.y);
    o.z = f2bf((v[c].z - mu) * rs * gv.z + bv.z);
    o.w = f2bf((v[c].w - mu) * rs * gv.w + bv.w);
    ((ushort4*)orow)[c * 64 + lane] = o;
  }
}

// ---------------- GEMM: C[M,N] = A[M,K]bf16 * Bt[N,K]bf16 + bias (+relu) (+resid) ----------------
template <int OUT_BF16, int RELU, int RESID>
__global__ __launch_bounds__(256) void gemm_k(const u16* __restrict__ A,
                                              const u16* __restrict__ Bt,
                                              const float* __restrict__ bias,
                                              const float* __restrict__ resid,
                                              void* __restrict__ Cout, int N, int K) {
  __shared__ u16 As[128 * 32];
  __shared__ u16 Bs[128 * 32];
  const int tid = threadIdx.x;
  const int m0 = blockIdx.x * 128;
  const int n0 = blockIdx.y * 128;
  const int lane = tid & 63, w = tid >> 6;
  const int wr = (w >> 1) * 64, wc = (w & 1) * 64;
  const int lhi = lane >> 4, llo = lane & 15;
  const int sr = tid >> 2, sc8 = (tid & 3) * 8;

  const u16* Ab = A + (size_t)(m0 + sr) * K + sc8;
  const u16* Bb = Bt + (size_t)(n0 + sr) * K + sc8;
  const size_t rstride = (size_t)64 * K;

  f32x4 acc[4][4] = {};

  for (int k0 = 0; k0 < K; k0 += 32) {
    __syncthreads();
    gload16(Ab + k0, (char*)As + tid * 16);
    gload16(Ab + rstride + k0, (char*)As + 4096 + tid * 16);
    gload16(Bb + k0, (char*)Bs + tid * 16);
    gload16(Bb + rstride + k0, (char*)Bs + 4096 + tid * 16);
    __syncthreads();
    bf16x8 af[4], bfr[4];
#pragma unroll
    for (int mi = 0; mi < 4; mi++) af[mi] = ld8(&As[(wr + mi * 16 + llo) * 32 + lhi * 8]);
#pragma unroll
    for (int ni = 0; ni < 4; ni++) bfr[ni] = ld8(&Bs[(wc + ni * 16 + llo) * 32 + lhi * 8]);
#pragma unroll
    for (int mi = 0; mi < 4; mi++)
#pragma unroll
      for (int ni = 0; ni < 4; ni++) acc[mi][ni] = MFMA(af[mi], bfr[ni], acc[mi][ni]);
  }

#pragma unroll
  for (int mi = 0; mi < 4; mi++)
#pragma unroll
    for (int ni = 0; ni < 4; ni++) {
      const int row = m0 + wr + mi * 16 + lhi * 4;
      const int col = n0 + wc + ni * 16 + llo;
      const float bsv = bias[col];
#pragma unroll
      for (int rr = 0; rr < 4; rr++) {
        float v = acc[mi][ni][rr] + bsv;
        if (RELU) v = fmaxf(v, 0.0f);
        const size_t idx = (size_t)(row + rr) * N + col;
        if (RESID) v += resid[idx];
        if (OUT_BF16)
          ((u16*)Cout)[idx] = f2bf(v);
        else
          ((float*)Cout)[idx] = v;
      }
    }
}

// ---------------- fused attention: qkv[B*N,2304]bf16 -> out[B*N,768]bf16 ----------------
// Q,K fragments direct from global (L2-resident); V transposed into swizzled LDS;
// P via per-wave swizzled LDS round-trip. Swizzle involution: koff ^= ((row&7)*8).
__global__ __launch_bounds__(256) void attn_k(const u16* __restrict__ qkv,
                                              u16* __restrict__ outp) {
  __shared__ u16 Vt[64 * 64];     // V^T[d][kv], kv-index swizzled by ((d&7)*8)
  __shared__ u16 Ps[4][16 * 64];  // per-wave P[qrow][kv], kv swizzled by ((qrow&7)*8)

  const int tid = threadIdx.x;
  const int qt = blockIdx.x;   // 0..15
  const int bh = blockIdx.y;   // 0..191
  const int b = bh / NH, h = bh % NH;
  const int lane = tid & 63, w = tid >> 6;
  const int lhi = lane >> 4, llo = lane & 15;
  const size_t rowb = (size_t)b * 1024;
  const float sscale = 0.03608439182435161f;  // 768^-0.5

  // Q fragments: loop-invariant, direct from global. A-frag row = llo (q-row of this wave)
  const u16* qrow = qkv + (rowb + qt * 64 + w * 16 + llo) * QKVN + h * HD;
  const bf16x8 qa0 = ld8(qrow + lhi * 8);
  const bf16x8 qa1 = ld8(qrow + 32 + lhi * 8);

  const u16* kbase = qkv + rowb * QKVN + DIMN + h * HD;
  const u16* vbase = qkv + rowb * QKVN + 2 * DIMN + h * HD;
  const int vc8 = w * 8;  // this thread stages V cols vc8..vc8+7 and vc8+32..vc8+39

  float mrow[4], lrow[4];
  f32x4 oacc[4] = {};
#pragma unroll
  for (int r = 0; r < 4; r++) {
    mrow[r] = -1e30f;
    lrow[r] = 0.f;
  }

  for (int kt = 0; kt < 16; kt++) {
    // ---- issue all global loads for this tile (no LDS deps) ----
    u16x8 v0 = *reinterpret_cast<const u16x8*>(vbase + (kt * 64 + lane) * QKVN + vc8);
    u16x8 v1 = *reinterpret_cast<const u16x8*>(vbase + (kt * 64 + lane) * QKVN + vc8 + 32);
    bf16x8 kf[2][4];
#pragma unroll
    for (int ks = 0; ks < 2; ks++)
#pragma unroll
      for (int ni = 0; ni < 4; ni++)
        kf[ks][ni] = ld8(kbase + (kt * 64 + ni * 16 + llo) * QKVN + ks * 32 + lhi * 8);

    __syncthreads();  // prev PV reads of Vt done
    // ---- transposed, swizzled V store: Vt[d][kv] at element d*64 + (kv ^ ((d&7)*8)) ----
#pragma unroll
    for (int j = 0; j < 8; j++) {
      Vt[(vc8 + j) * 64 + (lane ^ (j * 8))] = v0[j];
      Vt[(vc8 + 32 + j) * 64 + (lane ^ (j * 8))] = v1[j];
    }
    __syncthreads();  // Vt ready

    // ---- S = Q K^T ----
    f32x4 sacc[4] = {};
#pragma unroll
    for (int ni = 0; ni < 4; ni++) {
      sacc[ni] = MFMA(qa0, kf[0][ni], sacc[ni]);
      sacc[ni] = MFMA(qa1, kf[1][ni], sacc[ni]);
    }

    // ---- online softmax (thread owns q-rows lhi*4+r, kv cols llo+16*ni) ----
#pragma unroll
    for (int r = 0; r < 4; r++) {
      float s0 = sacc[0][r] * sscale, s1 = sacc[1][r] * sscale;
      float s2 = sacc[2][r] * sscale, s3 = sacc[3][r] * sscale;
      float sm = fmaxf(fmaxf(s0, s1), fmaxf(s2, s3));
      sm = fmaxf(sm, __shfl_xor(sm, 1));
      sm = fmaxf(sm, __shfl_xor(sm, 2));
      sm = fmaxf(sm, __shfl_xor(sm, 4));
      sm = fmaxf(sm, __shfl_xor(sm, 8));
      float mnew = fmaxf(mrow[r], sm);
      float scale = __expf(mrow[r] - mnew);
      mrow[r] = mnew;
      float p0 = __expf(s0 - mnew), p1 = __expf(s1 - mnew);
      float p2 = __expf(s2 - mnew), p3 = __expf(s3 - mnew);
      float ps = p0 + p1 + p2 + p3;
      ps += __shfl_xor(ps, 1);
      ps += __shfl_xor(ps, 2);
      ps += __shfl_xor(ps, 4);
      ps += __shfl_xor(ps, 8);
      lrow[r] = lrow[r] * scale + ps;
#pragma unroll
      for (int ni = 0; ni < 4; ni++) oacc[ni][r] *= scale;
      const int row = lhi * 4 + r;
      const int sw = (row & 7) * 8;
      u16* prow = &Ps[w][row * 64];
      prow[llo ^ sw] = f2bf(p0);
      prow[(llo + 16) ^ sw] = f2bf(p1);
      prow[(llo + 32) ^ sw] = f2bf(p2);
      prow[(llo + 48) ^ sw] = f2bf(p3);
    }
    // no __syncthreads needed: Ps is per-wave; lgkmcnt orders within-wave RAW

    // ---- O += P V ----
#pragma unroll
    for (int ks = 0; ks < 2; ks++) {
      const int koff = ks * 32 + lhi * 8;
      bf16x8 pa = ld8(&Ps[w][llo * 64 + (koff ^ ((llo & 7) * 8))]);
#pragma unroll
      for (int ni = 0; ni < 4; ni++) {
        bf16x8 vb = ld8(&Vt[(ni * 16 + llo) * 64 + (koff ^ ((llo & 7) * 8))]);
        oacc[ni] = MFMA(pa, vb, oacc[ni]);
      }
    }
  }

#pragma unroll
  for (int ni = 0; ni < 4; ni++)
#pragma unroll
    for (int r = 0; r < 4; r++) {
      const size_t row = rowb + qt * 64 + w * 16 + lhi * 4 + r;
      outp[row * DIMN + h * HD + ni * 16 + llo] = f2bf(oacc[ni][r] / lrow[r]);
    }
}

extern "C" void kernel_launch(void* const* d_in, const int* in_sizes, int n_in,
                              void* d_out, int out_size, void* d_ws, size_t ws_size,
                              hipStream_t stream) {
  const float* x = (const float*)d_in[0];
  const float* Wqkv = (const float*)d_in[1];
  const float* bqkv = (const float*)d_in[2];
  const float* Wproj = (const float*)d_in[3];
  const float* bproj = (const float*)d_in[4];
  const float* g1 = (const float*)d_in[5];
  const float* b1 = (const float*)d_in[6];
  const float* g2 = (const float*)d_in[7];
  const float* b2 = (const float*)d_in[8];
  const float* W1 = (const float*)d_in[9];
  const float* bf1 = (const float*)d_in[10];
  const float* W2 = (const float*)d_in[11];
  const float* bf2 = (const float*)d_in[12];
  float* outp = (float*)d_out;

  char* p = (char*)d_ws;
  u16* WqkvT = (u16*)p; p += (size_t)QKVN * DIMN * 2;
  u16* WprojT = (u16*)p; p += (size_t)DIMN * DIMN * 2;
  u16* W1T = (u16*)p; p += (size_t)HID * DIMN * 2;
  u16* W2T = (u16*)p; p += (size_t)DIMN * HID * 2;
  u16* bufX = (u16*)p; p += (size_t)BNROWS * DIMN * 2;  // h1 / attn_out / h2
  u16* big = (u16*)p; p += (size_t)BNROWS * HID * 2;    // qkv then ff1

  // weight transposes (fp32 -> bf16, [K,N] -> [N,K])
  twb_k<<<dim3(QKVN / 32, DIMN / 32), 256, 0, stream>>>(Wqkv, WqkvT, DIMN, QKVN);
  twb_k<<<dim3(DIMN / 32, DIMN / 32), 256, 0, stream>>>(Wproj, WprojT, DIMN, DIMN);
  twb_k<<<dim3(HID / 32, DIMN / 32), 256, 0, stream>>>(W1, W1T, DIMN, HID);
  twb_k<<<dim3(DIMN / 32, HID / 32), 256, 0, stream>>>(W2, W2T, HID, DIMN);

  // LN1
  ln_k<<<BNROWS / 4, 256, 0, stream>>>(x, g1, b1, bufX);
  // QKV GEMM -> big (bf16)
  gemm_k<1, 0, 0><<<dim3(128, QKVN / 128), 256, 0, stream>>>(bufX, WqkvT, bqkv, nullptr,
                                                             big, QKVN, DIMN);
  // attention -> bufX (bf16)
  attn_k<<<dim3(16, 16 * NH), 256, 0, stream>>>(big, bufX);
  // proj GEMM + residual(x) -> d_out (fp32)
  gemm_k<0, 0, 1><<<dim3(128, DIMN / 128), 256, 0, stream>>>(bufX, WprojT, bproj, x, outp,
                                                             DIMN, DIMN);
  // LN2
  ln_k<<<BNROWS / 4, 256, 0, stream>>>(outp, g2, b2, bufX);
  // FF1 (relu) -> big (bf16)
  gemm_k<1, 1, 0><<<dim3(128, HID / 128), 256, 0, stream>>>(bufX, W1T, bf1, nullptr, big,
                                                            HID, DIMN);
  // FF2 + residual(d_out) -> d_out (fp32, in place)
  gemm_k<0, 0, 1><<<dim3(128, DIMN / 128), 256, 0, stream>>>(big, W2T, bf2, outp, outp,
                                                             DIMN, HID);
}

// Round 3
// 580.076 us; speedup vs baseline: 1.2953x; 1.1969x over previous
//
#include <hip/hip_runtime.h>
#include <cstdint>
#include <cstddef>

typedef unsigned short u16;
typedef __bf16 bf16x8 __attribute__((ext_vector_type(8)));
typedef unsigned short u16x8 __attribute__((ext_vector_type(8)));
typedef float f32x4 __attribute__((ext_vector_type(4)));

#define DIMN 768
#define BNROWS 16384
#define NH 12
#define HD 64
#define HID 3072
#define QKVN 2304

__device__ __forceinline__ u16 f2bf(float f) {
  unsigned u = __builtin_bit_cast(unsigned, f);
  u += 0x7fffu + ((u >> 16) & 1u);
  return (u16)(u >> 16);
}

__device__ __forceinline__ bf16x8 ld8(const u16* p) {
  u16x8 v = *reinterpret_cast<const u16x8*>(p);
  return __builtin_bit_cast(bf16x8, v);
}

__device__ __forceinline__ void gload16(const void* g, void* l) {
  __builtin_amdgcn_global_load_lds(
      (const __attribute__((address_space(1))) unsigned int*)g,
      (__attribute__((address_space(3))) unsigned int*)l, 16, 0, 0);
}

#define MFMA(a, b, c) __builtin_amdgcn_mfma_f32_16x16x32_bf16(a, b, c, 0, 0, 0)

// ---------------- weight transpose + cast: W[K,N] f32 -> Wt[N,K] bf16 ----------------
__global__ __launch_bounds__(256) void twb_k(const float* __restrict__ W,
                                             u16* __restrict__ Wt, int K, int N) {
  __shared__ float tile[32][33];
  const int n0 = blockIdx.x * 32, k0 = blockIdx.y * 32;
  const int tx = threadIdx.x & 31, ty = threadIdx.x >> 5;  // ty 0..7
#pragma unroll
  for (int i = 0; i < 4; i++)
    tile[ty + i * 8][tx] = W[(size_t)(k0 + ty + i * 8) * N + n0 + tx];
  __syncthreads();
#pragma unroll
  for (int i = 0; i < 4; i++)
    Wt[(size_t)(n0 + ty + i * 8) * K + k0 + tx] = f2bf(tile[tx][ty + i * 8]);
}

// ---------------- LayerNorm: fp32 row -> bf16 row (one wave per 768-row) ----------------
__global__ __launch_bounds__(256) void ln_k(const float* __restrict__ x,
                                            const float* __restrict__ g,
                                            const float* __restrict__ bta,
                                            u16* __restrict__ outp) {
  const int row = blockIdx.x * 4 + (threadIdx.x >> 6);
  const int lane = threadIdx.x & 63;
  const float4* xr = (const float4*)(x + (size_t)row * DIMN);
  float4 v[3];
  float s = 0.f, ss = 0.f;
#pragma unroll
  for (int c = 0; c < 3; c++) {
    v[c] = xr[c * 64 + lane];
    s += v[c].x + v[c].y + v[c].z + v[c].w;
    ss += v[c].x * v[c].x + v[c].y * v[c].y + v[c].z * v[c].z + v[c].w * v[c].w;
  }
#pragma unroll
  for (int off = 1; off < 64; off <<= 1) {
    s += __shfl_xor(s, off);
    ss += __shfl_xor(ss, off);
  }
  const float mu = s * (1.f / DIMN);
  const float var = ss * (1.f / DIMN) - mu * mu;
  const float rs = rsqrtf(var + 1e-5f);
  u16* orow = outp + (size_t)row * DIMN;
#pragma unroll
  for (int c = 0; c < 3; c++) {
    float4 gv = ((const float4*)g)[c * 64 + lane];
    float4 bv = ((const float4*)bta)[c * 64 + lane];
    ushort4 o;
    o.x = f2bf((v[c].x - mu) * rs * gv.x + bv.x);
    o.y = f2bf((v[c].y - mu) * rs * gv.y + bv.y);
    o.z = f2bf((v[c].z - mu) * rs * gv.z + bv.z);
    o.w = f2bf((v[c].w - mu) * rs * gv.w + bv.w);
    ((ushort4*)orow)[c * 64 + lane] = o;
  }
}

// ---------------- GEMM: C[M,N] = A[M,K]bf16 * Bt[N,K]bf16 + bias (+relu) (+resid) ----------------
template <int OUT_BF16, int RELU, int RESID>
__global__ __launch_bounds__(256) void gemm_k(const u16* __restrict__ A,
                                              const u16* __restrict__ Bt,
                                              const float* __restrict__ bias,
                                              const float* __restrict__ resid,
                                              void* __restrict__ Cout, int N, int K) {
  __shared__ u16 As[128 * 32];
  __shared__ u16 Bs[128 * 32];
  const int tid = threadIdx.x;
  const int m0 = blockIdx.x * 128;
  const int n0 = blockIdx.y * 128;
  const int lane = tid & 63, w = tid >> 6;
  const int wr = (w >> 1) * 64, wc = (w & 1) * 64;
  const int lhi = lane >> 4, llo = lane & 15;
  const int sr = tid >> 2, sc8 = (tid & 3) * 8;

  const u16* Ab = A + (size_t)(m0 + sr) * K + sc8;
  const u16* Bb = Bt + (size_t)(n0 + sr) * K + sc8;
  const size_t rstride = (size_t)64 * K;

  f32x4 acc[4][4] = {};

  for (int k0 = 0; k0 < K; k0 += 32) {
    __syncthreads();
    gload16(Ab + k0, (char*)As + tid * 16);
    gload16(Ab + rstride + k0, (char*)As + 4096 + tid * 16);
    gload16(Bb + k0, (char*)Bs + tid * 16);
    gload16(Bb + rstride + k0, (char*)Bs + 4096 + tid * 16);
    __syncthreads();
    bf16x8 af[4], bfr[4];
#pragma unroll
    for (int mi = 0; mi < 4; mi++) af[mi] = ld8(&As[(wr + mi * 16 + llo) * 32 + lhi * 8]);
#pragma unroll
    for (int ni = 0; ni < 4; ni++) bfr[ni] = ld8(&Bs[(wc + ni * 16 + llo) * 32 + lhi * 8]);
#pragma unroll
    for (int mi = 0; mi < 4; mi++)
#pragma unroll
      for (int ni = 0; ni < 4; ni++) acc[mi][ni] = MFMA(af[mi], bfr[ni], acc[mi][ni]);
  }

#pragma unroll
  for (int mi = 0; mi < 4; mi++)
#pragma unroll
    for (int ni = 0; ni < 4; ni++) {
      const int row = m0 + wr + mi * 16 + lhi * 4;
      const int col = n0 + wc + ni * 16 + llo;
      const float bsv = bias[col];
#pragma unroll
      for (int rr = 0; rr < 4; rr++) {
        float v = acc[mi][ni][rr] + bsv;
        if (RELU) v = fmaxf(v, 0.0f);
        const size_t idx = (size_t)(row + rr) * N + col;
        if (RESID) v += resid[idx];
        if (OUT_BF16)
          ((u16*)Cout)[idx] = f2bf(v);
        else
          ((float*)Cout)[idx] = v;
      }
    }
}

// ---------------- fused attention ----------------
// QBLK=128, 4 waves x 32 q-rows. Swapped QK^T (S^T = mfma(K,Q)) -> no-max softmax
// (scores bounded, prescaled by 768^-0.5*log2e) -> P via b32 swizzled LDS -> PV.
// Grid is flat-swizzled so all 8 q-blocks of one (b,h) land on one XCD (K/V L2 reuse).
__device__ __forceinline__ bf16x8 ldscale8(const u16* p, float c) {
  u16x8 v = *reinterpret_cast<const u16x8*>(p);
  bf16x8 r;
#pragma unroll
  for (int j = 0; j < 8; j++) {
    float f = __builtin_bit_cast(float, (unsigned)v[j] << 16) * c;
    r[j] = (__bf16)f;
  }
  return r;
}

__device__ __forceinline__ unsigned pack_bf2(float a, float b) {
  unsigned ua = (unsigned)__builtin_bit_cast(u16, (__bf16)a);
  unsigned ub = (unsigned)__builtin_bit_cast(u16, (__bf16)b);
  return ua | (ub << 16);
}

__global__ __launch_bounds__(256) void attn_k(const u16* __restrict__ qkv,
                                              u16* __restrict__ outp) {
  __shared__ u16 Vt[64 * 64];      // V^T[d][kv], kv swizzled by ((d&7)*8)
  __shared__ u16 Ps[4][32 * 64];   // per-wave P[q][kv], kv swizzled by ((q&7)*8)

  const int tid = threadIdx.x;
  const int f = blockIdx.x;                    // 0..1535
  const int bh = (f & 7) | ((f >> 6) << 3);    // all qt of one bh on one XCD
  const int qt = (f >> 3) & 7;
  const int b = bh / NH, h = bh - b * NH;
  const int lane = tid & 63, w = tid >> 6;
  const int lhi = lane >> 4, llo = lane & 15;
  const size_t rowb = (size_t)b * 1024;
  const int wq0 = qt * 128 + w * 32;
  const float SC = 0.052059750f;  // 768^-0.5 * log2(e)

  // Q fragments (B-operand of swapped QK^T), prescaled, loop-invariant
  bf16x8 qb[2][2];
#pragma unroll
  for (int mi = 0; mi < 2; mi++) {
    const u16* qrow = qkv + (rowb + wq0 + mi * 16 + llo) * QKVN + h * HD;
    qb[mi][0] = ldscale8(qrow + lhi * 8, SC);
    qb[mi][1] = ldscale8(qrow + 32 + lhi * 8, SC);
  }

  const u16* kbase = qkv + rowb * QKVN + DIMN + h * HD;
  const u16* vbase = qkv + rowb * QKVN + 2 * DIMN + h * HD;
  const int vc8 = w * 8;
  const int sw = (llo & 7) * 8;

  float psum[2] = {0.f, 0.f};
  f32x4 oacc[2][4] = {};

  for (int kt = 0; kt < 16; kt++) {
    // issue all global loads for this tile
    u16x8 v0 = *reinterpret_cast<const u16x8*>(vbase + (kt * 64 + lane) * QKVN + vc8);
    u16x8 v1 = *reinterpret_cast<const u16x8*>(vbase + (kt * 64 + lane) * QKVN + vc8 + 32);
    bf16x8 kf[2][4];
#pragma unroll
    for (int ks = 0; ks < 2; ks++)
#pragma unroll
      for (int ni = 0; ni < 4; ni++)
        kf[ks][ni] = ld8(kbase + (kt * 64 + ni * 16 + llo) * QKVN + ks * 32 + lhi * 8);

    __syncthreads();  // prev PV reads of Vt done
#pragma unroll
    for (int j = 0; j < 8; j++) {
      Vt[(vc8 + j) * 64 + (lane ^ (j * 8))] = v0[j];
      Vt[(vc8 + 32 + j) * 64 + (lane ^ (j * 8))] = v1[j];
    }
    __syncthreads();  // Vt ready

    // S^T = K Q^T : sacc[ni][mi] holds (kv=ni*16+lhi*4+r, q=mi*16+llo)
    f32x4 sacc[4][2] = {};
#pragma unroll
    for (int ks = 0; ks < 2; ks++)
#pragma unroll
      for (int ni = 0; ni < 4; ni++)
#pragma unroll
        for (int mi = 0; mi < 2; mi++)
          sacc[ni][mi] = MFMA(kf[ks][ni], qb[mi][ks], sacc[ni][mi]);

    // P = 2^(S'), no max-subtraction (bounded scores); partial row sums deferred
#pragma unroll
    for (int mi = 0; mi < 2; mi++)
#pragma unroll
      for (int ni = 0; ni < 4; ni++) {
        float p0 = __builtin_amdgcn_exp2f(sacc[ni][mi][0]);
        float p1 = __builtin_amdgcn_exp2f(sacc[ni][mi][1]);
        float p2 = __builtin_amdgcn_exp2f(sacc[ni][mi][2]);
        float p3 = __builtin_amdgcn_exp2f(sacc[ni][mi][3]);
        psum[mi] += (p0 + p1) + (p2 + p3);
        u16* pp = &Ps[w][(mi * 16 + llo) * 64 + ((ni * 16 + lhi * 4) ^ sw)];
        ((unsigned*)pp)[0] = pack_bf2(p0, p1);
        ((unsigned*)pp)[1] = pack_bf2(p2, p3);
      }
    // Ps is per-wave: within-wave lgkmcnt ordering suffices, no barrier

    // O += P V
#pragma unroll
    for (int ks = 0; ks < 2; ks++) {
      const int koff = ks * 32 + lhi * 8;
      bf16x8 pa0 = ld8(&Ps[w][llo * 64 + (koff ^ sw)]);
      bf16x8 pa1 = ld8(&Ps[w][(16 + llo) * 64 + (koff ^ sw)]);
#pragma unroll
      for (int ni = 0; ni < 4; ni++) {
        bf16x8 vb = ld8(&Vt[(ni * 16 + llo) * 64 + (koff ^ sw)]);
        oacc[0][ni] = MFMA(pa0, vb, oacc[0][ni]);
        oacc[1][ni] = MFMA(pa1, vb, oacc[1][ni]);
      }
    }
  }

  // full row sums: reduce across lhi groups, then lane-transpose to output rows
  float rl[2][4];
#pragma unroll
  for (int mi = 0; mi < 2; mi++) {
    psum[mi] += __shfl_xor(psum[mi], 16);
    psum[mi] += __shfl_xor(psum[mi], 32);
#pragma unroll
    for (int r = 0; r < 4; r++) rl[mi][r] = 1.0f / __shfl(psum[mi], lhi * 4 + r);
  }

#pragma unroll
  for (int mi = 0; mi < 2; mi++)
#pragma unroll
    for (int ni = 0; ni < 4; ni++)
#pragma unroll
      for (int r = 0; r < 4; r++) {
        const size_t row = rowb + wq0 + mi * 16 + lhi * 4 + r;
        outp[row * DIMN + h * HD + ni * 16 + llo] = f2bf(oacc[mi][ni][r] * rl[mi][r]);
      }
}

extern "C" void kernel_launch(void* const* d_in, const int* in_sizes, int n_in,
                              void* d_out, int out_size, void* d_ws, size_t ws_size,
                              hipStream_t stream) {
  const float* x = (const float*)d_in[0];
  const float* Wqkv = (const float*)d_in[1];
  const float* bqkv = (const float*)d_in[2];
  const float* Wproj = (const float*)d_in[3];
  const float* bproj = (const float*)d_in[4];
  const float* g1 = (const float*)d_in[5];
  const float* b1 = (const float*)d_in[6];
  const float* g2 = (const float*)d_in[7];
  const float* b2 = (const float*)d_in[8];
  const float* W1 = (const float*)d_in[9];
  const float* bf1 = (const float*)d_in[10];
  const float* W2 = (const float*)d_in[11];
  const float* bf2 = (const float*)d_in[12];
  float* outp = (float*)d_out;

  char* p = (char*)d_ws;
  u16* WqkvT = (u16*)p; p += (size_t)QKVN * DIMN * 2;
  u16* WprojT = (u16*)p; p += (size_t)DIMN * DIMN * 2;
  u16* W1T = (u16*)p; p += (size_t)HID * DIMN * 2;
  u16* W2T = (u16*)p; p += (size_t)DIMN * HID * 2;
  u16* bufX = (u16*)p; p += (size_t)BNROWS * DIMN * 2;  // h1 / attn_out / h2
  u16* big = (u16*)p; p += (size_t)BNROWS * HID * 2;    // qkv then ff1

  // weight transposes (fp32 -> bf16, [K,N] -> [N,K])
  twb_k<<<dim3(QKVN / 32, DIMN / 32), 256, 0, stream>>>(Wqkv, WqkvT, DIMN, QKVN);
  twb_k<<<dim3(DIMN / 32, DIMN / 32), 256, 0, stream>>>(Wproj, WprojT, DIMN, DIMN);
  twb_k<<<dim3(HID / 32, DIMN / 32), 256, 0, stream>>>(W1, W1T, DIMN, HID);
  twb_k<<<dim3(DIMN / 32, HID / 32), 256, 0, stream>>>(W2, W2T, HID, DIMN);

  // LN1
  ln_k<<<BNROWS / 4, 256, 0, stream>>>(x, g1, b1, bufX);
  // QKV GEMM -> big (bf16)
  gemm_k<1, 0, 0><<<dim3(128, QKVN / 128), 256, 0, stream>>>(bufX, WqkvT, bqkv, nullptr,
                                                             big, QKVN, DIMN);
  // attention -> bufX (bf16)
  attn_k<<<1536, 256, 0, stream>>>(big, bufX);
  // proj GEMM + residual(x) -> d_out (fp32)
  gemm_k<0, 0, 1><<<dim3(128, DIMN / 128), 256, 0, stream>>>(bufX, WprojT, bproj, x, outp,
                                                             DIMN, DIMN);
  // LN2
  ln_k<<<BNROWS / 4, 256, 0, stream>>>(outp, g2, b2, bufX);
  // FF1 (relu) -> big (bf16)
  gemm_k<1, 1, 0><<<dim3(128, HID / 128), 256, 0, stream>>>(bufX, W1T, bf1, nullptr, big,
                                                            HID, DIMN);
  // FF2 + residual(d_out) -> d_out (fp32, in place)
  gemm_k<0, 0, 1><<<dim3(128, DIMN / 128), 256, 0, stream>>>(big, W2T, bf2, outp, outp,
                                                             DIMN, HID);
}

// Round 4
// 495.631 us; speedup vs baseline: 1.5159x; 1.1704x over previous
//
#include <hip/hip_runtime.h>
#include <cstdint>
#include <cstddef>

typedef unsigned short u16;
typedef __bf16 bf16x8 __attribute__((ext_vector_type(8)));
typedef unsigned short u16x8 __attribute__((ext_vector_type(8)));
typedef float f32x4 __attribute__((ext_vector_type(4)));

#define DIMN 768
#define BNROWS 16384
#define NH 12
#define HD 64
#define HID 3072
#define QKVN 2304

__device__ __forceinline__ u16 f2bf(float f) {
  unsigned u = __builtin_bit_cast(unsigned, f);
  u += 0x7fffu + ((u >> 16) & 1u);
  return (u16)(u >> 16);
}

__device__ __forceinline__ bf16x8 ld8(const u16* p) {
  u16x8 v = *reinterpret_cast<const u16x8*>(p);
  return __builtin_bit_cast(bf16x8, v);
}

__device__ __forceinline__ void gload16(const void* g, void* l) {
  __builtin_amdgcn_global_load_lds(
      (const __attribute__((address_space(1))) unsigned int*)g,
      (__attribute__((address_space(3))) unsigned int*)l, 16, 0, 0);
}

#define MFMA(a, b, c) __builtin_amdgcn_mfma_f32_16x16x32_bf16(a, b, c, 0, 0, 0)

// ---------------- weight transpose + cast: W[K,N] f32 -> Wt[N,K] bf16 ----------------
__global__ __launch_bounds__(256) void twb_k(const float* __restrict__ W,
                                             u16* __restrict__ Wt, int K, int N) {
  __shared__ float tile[32][33];
  const int n0 = blockIdx.x * 32, k0 = blockIdx.y * 32;
  const int tx = threadIdx.x & 31, ty = threadIdx.x >> 5;  // ty 0..7
#pragma unroll
  for (int i = 0; i < 4; i++)
    tile[ty + i * 8][tx] = W[(size_t)(k0 + ty + i * 8) * N + n0 + tx];
  __syncthreads();
#pragma unroll
  for (int i = 0; i < 4; i++)
    Wt[(size_t)(n0 + ty + i * 8) * K + k0 + tx] = f2bf(tile[tx][ty + i * 8]);
}

// ---------------- LayerNorm: fp32 row -> bf16 row (one wave per 768-row) ----------------
__global__ __launch_bounds__(256) void ln_k(const float* __restrict__ x,
                                            const float* __restrict__ g,
                                            const float* __restrict__ bta,
                                            u16* __restrict__ outp) {
  const int row = blockIdx.x * 4 + (threadIdx.x >> 6);
  const int lane = threadIdx.x & 63;
  const float4* xr = (const float4*)(x + (size_t)row * DIMN);
  float4 v[3];
  float s = 0.f, ss = 0.f;
#pragma unroll
  for (int c = 0; c < 3; c++) {
    v[c] = xr[c * 64 + lane];
    s += v[c].x + v[c].y + v[c].z + v[c].w;
    ss += v[c].x * v[c].x + v[c].y * v[c].y + v[c].z * v[c].z + v[c].w * v[c].w;
  }
#pragma unroll
  for (int off = 1; off < 64; off <<= 1) {
    s += __shfl_xor(s, off);
    ss += __shfl_xor(ss, off);
  }
  const float mu = s * (1.f / DIMN);
  const float var = ss * (1.f / DIMN) - mu * mu;
  const float rs = rsqrtf(var + 1e-5f);
  u16* orow = outp + (size_t)row * DIMN;
#pragma unroll
  for (int c = 0; c < 3; c++) {
    float4 gv = ((const float4*)g)[c * 64 + lane];
    float4 bv = ((const float4*)bta)[c * 64 + lane];
    ushort4 o;
    o.x = f2bf((v[c].x - mu) * rs * gv.x + bv.x);
    o.y = f2bf((v[c].y - mu) * rs * gv.y + bv.y);
    o.z = f2bf((v[c].z - mu) * rs * gv.z + bv.z);
    o.w = f2bf((v[c].w - mu) * rs * gv.w + bv.w);
    ((ushort4*)orow)[c * 64 + lane] = o;
  }
}

// ---------------- GEMM 256x256, 8 waves, BK=32, 4-slot LDS ring, counted vmcnt ----------
// C[M,N] = A[M,K]bf16 * Bt[N,K]bf16 + bias (+relu) (+resid). Raw s_barrier (no compiler
// vmcnt(0) drain); per K-tile: 2 phases x 16 MFMA; stage tile t+3 (2 gload_lds per phase);
// boundary wait vmcnt(8) steady / 4 / 0 in tail. WAR ledger: slot (t+3)&3 was last read
// at tile t-1; every wave drains lgkmcnt before its closing barrier, so stage issue at
// tile t (after that barrier) is safe.
template <int OUT_BF16, int RELU, int RESID>
__global__ __launch_bounds__(512, 2) void gemm256_k(const u16* __restrict__ A,
                                                    const u16* __restrict__ Bt,
                                                    const float* __restrict__ bias,
                                                    const float* __restrict__ resid,
                                                    void* __restrict__ Cout, int N, int K) {
  __shared__ u16 lds[65536];  // 4 slots x (A 16KB + B 16KB) = 128 KiB
  const int tid = threadIdx.x;
  const int m0 = blockIdx.x * 256;
  const int n0 = blockIdx.y * 256;
  const int lane = tid & 63, w = tid >> 6;
  const int wr = w >> 2, wc = w & 3;  // 2 (M) x 4 (N) wave grid, per-wave C = 128x64
  const int lhi = lane >> 4, llo = lane & 15;
  const int NT = K >> 5;

  // staging: per tile each thread loads 2 A-chunks + 2 B-chunks (16B each), linear LDS
  const int srow = tid >> 2, sc8 = (tid & 3) * 8;
  const u16* aS0 = A + (size_t)(m0 + srow) * K + sc8;
  const u16* aS1 = A + (size_t)(m0 + 128 + srow) * K + sc8;
  const u16* bS0 = Bt + (size_t)(n0 + srow) * K + sc8;
  const u16* bS1 = Bt + (size_t)(n0 + 128 + srow) * K + sc8;

  auto slotBase = [&](int t) -> char* { return (char*)lds + ((size_t)(t & 3) << 15); };
  auto stageA = [&](int t) {
    char* sb = slotBase(t);
    gload16(aS0 + t * 32, sb + tid * 16);
    gload16(aS1 + t * 32, sb + 8192 + tid * 16);
  };
  auto stageB = [&](int t) {
    char* sb = slotBase(t) + 16384;
    gload16(bS0 + t * 32, sb + tid * 16);
    gload16(bS1 + t * 32, sb + 8192 + tid * 16);
  };

  f32x4 acc[8][4] = {};

  // prologue: tiles 0,1,2 in flight (12 loads); wait slot0 landed
  stageA(0); stageB(0);
  stageA(1); stageB(1);
  stageA(2); stageB(2);
  asm volatile("s_waitcnt vmcnt(8)" ::: "memory");
  __builtin_amdgcn_s_barrier();

  for (int t = 0; t < NT; ++t) {
    const char* sb = slotBase(t);
    // ---- phase 1: read A ms-half0 + all B; compute acc[0..3][*] ----
    bf16x8 af[4], bfr[4];
#pragma unroll
    for (int ni = 0; ni < 4; ni++)
      bfr[ni] = ld8((const u16*)(sb + 16384 + (wc * 64 + ni * 16 + llo) * 64 + lhi * 16));
#pragma unroll
    for (int mi = 0; mi < 4; mi++)
      af[mi] = ld8((const u16*)(sb + (wr * 128 + mi * 16 + llo) * 64 + lhi * 16));
    if (t + 3 < NT) stageA(t + 3);
    __builtin_amdgcn_s_barrier();
    asm volatile("s_waitcnt lgkmcnt(0)" ::: "memory");
    __builtin_amdgcn_sched_barrier(0);
    __builtin_amdgcn_s_setprio(1);
#pragma unroll
    for (int mi = 0; mi < 4; mi++)
#pragma unroll
      for (int ni = 0; ni < 4; ni++) acc[mi][ni] = MFMA(af[mi], bfr[ni], acc[mi][ni]);
    __builtin_amdgcn_s_setprio(0);
    __builtin_amdgcn_sched_barrier(0);
    __builtin_amdgcn_s_barrier();
    // ---- phase 2: read A ms-half1; compute acc[4..7][*] ----
#pragma unroll
    for (int mi = 0; mi < 4; mi++)
      af[mi] = ld8((const u16*)(sb + (wr * 128 + 64 + mi * 16 + llo) * 64 + lhi * 16));
    if (t + 3 < NT) stageB(t + 3);
    __builtin_amdgcn_s_barrier();
    asm volatile("s_waitcnt lgkmcnt(0)" ::: "memory");
    __builtin_amdgcn_sched_barrier(0);
    __builtin_amdgcn_s_setprio(1);
#pragma unroll
    for (int mi = 0; mi < 4; mi++)
#pragma unroll
      for (int ni = 0; ni < 4; ni++) acc[4 + mi][ni] = MFMA(af[mi], bfr[ni], acc[4 + mi][ni]);
    __builtin_amdgcn_s_setprio(0);
    __builtin_amdgcn_sched_barrier(0);
    // ---- K-tile boundary: drain tile t+1 only (counted, never 0 in steady state) ----
    if (t + 3 < NT) {
      asm volatile("s_waitcnt vmcnt(8)" ::: "memory");
    } else if (t + 2 < NT) {
      asm volatile("s_waitcnt vmcnt(4)" ::: "memory");
    } else if (t + 1 < NT) {
      asm volatile("s_waitcnt vmcnt(0)" ::: "memory");
    }
    __builtin_amdgcn_s_barrier();
  }

  // ---- epilogue ----
#pragma unroll
  for (int mi = 0; mi < 8; mi++)
#pragma unroll
    for (int ni = 0; ni < 4; ni++) {
      const int row = m0 + wr * 128 + mi * 16 + lhi * 4;
      const int col = n0 + wc * 64 + ni * 16 + llo;
      const float bsv = bias[col];
#pragma unroll
      for (int rr = 0; rr < 4; rr++) {
        float v = acc[mi][ni][rr] + bsv;
        if (RELU) v = fmaxf(v, 0.0f);
        const size_t idx = (size_t)(row + rr) * N + col;
        if (RESID) v += resid[idx];
        if (OUT_BF16)
          ((u16*)Cout)[idx] = f2bf(v);
        else
          ((float*)Cout)[idx] = v;
      }
    }
}

// ---------------- fused attention ----------------
// QBLK=128, 4 waves x 32 q-rows. Swapped QK^T (S^T = mfma(K,Q)) -> no-max softmax
// (scores bounded, prescaled by 768^-0.5*log2e) -> P via b32 swizzled LDS -> PV.
// Grid is flat-swizzled so all 8 q-blocks of one (b,h) land on one XCD (K/V L2 reuse).
__device__ __forceinline__ bf16x8 ldscale8(const u16* p, float c) {
  u16x8 v = *reinterpret_cast<const u16x8*>(p);
  bf16x8 r;
#pragma unroll
  for (int j = 0; j < 8; j++) {
    float f = __builtin_bit_cast(float, (unsigned)v[j] << 16) * c;
    r[j] = (__bf16)f;
  }
  return r;
}

__device__ __forceinline__ unsigned pack_bf2(float a, float b) {
  unsigned ua = (unsigned)__builtin_bit_cast(u16, (__bf16)a);
  unsigned ub = (unsigned)__builtin_bit_cast(u16, (__bf16)b);
  return ua | (ub << 16);
}

__global__ __launch_bounds__(256) void attn_k(const u16* __restrict__ qkv,
                                              u16* __restrict__ outp) {
  __shared__ u16 Vt[64 * 64];      // V^T[d][kv], kv swizzled by ((d&7)*8)
  __shared__ u16 Ps[4][32 * 64];   // per-wave P[q][kv], kv swizzled by ((q&7)*8)

  const int tid = threadIdx.x;
  const int f = blockIdx.x;                    // 0..1535
  const int bh = (f & 7) | ((f >> 6) << 3);    // all qt of one bh on one XCD
  const int qt = (f >> 3) & 7;
  const int b = bh / NH, h = bh - b * NH;
  const int lane = tid & 63, w = tid >> 6;
  const int lhi = lane >> 4, llo = lane & 15;
  const size_t rowb = (size_t)b * 1024;
  const int wq0 = qt * 128 + w * 32;
  const float SC = 0.052059750f;  // 768^-0.5 * log2(e)

  // Q fragments (B-operand of swapped QK^T), prescaled, loop-invariant
  bf16x8 qb[2][2];
#pragma unroll
  for (int mi = 0; mi < 2; mi++) {
    const u16* qrow = qkv + (rowb + wq0 + mi * 16 + llo) * QKVN + h * HD;
    qb[mi][0] = ldscale8(qrow + lhi * 8, SC);
    qb[mi][1] = ldscale8(qrow + 32 + lhi * 8, SC);
  }

  const u16* kbase = qkv + rowb * QKVN + DIMN + h * HD;
  const u16* vbase = qkv + rowb * QKVN + 2 * DIMN + h * HD;
  const int vc8 = w * 8;
  const int sw = (llo & 7) * 8;

  float psum[2] = {0.f, 0.f};
  f32x4 oacc[2][4] = {};

  for (int kt = 0; kt < 16; kt++) {
    // issue all global loads for this tile
    u16x8 v0 = *reinterpret_cast<const u16x8*>(vbase + (kt * 64 + lane) * QKVN + vc8);
    u16x8 v1 = *reinterpret_cast<const u16x8*>(vbase + (kt * 64 + lane) * QKVN + vc8 + 32);
    bf16x8 kf[2][4];
#pragma unroll
    for (int ks = 0; ks < 2; ks++)
#pragma unroll
      for (int ni = 0; ni < 4; ni++)
        kf[ks][ni] = ld8(kbase + (kt * 64 + ni * 16 + llo) * QKVN + ks * 32 + lhi * 8);

    __syncthreads();  // prev PV reads of Vt done
#pragma unroll
    for (int j = 0; j < 8; j++) {
      Vt[(vc8 + j) * 64 + (lane ^ (j * 8))] = v0[j];
      Vt[(vc8 + 32 + j) * 64 + (lane ^ (j * 8))] = v1[j];
    }
    __syncthreads();  // Vt ready

    // S^T = K Q^T : sacc[ni][mi] holds (kv=ni*16+lhi*4+r, q=mi*16+llo)
    f32x4 sacc[4][2] = {};
#pragma unroll
    for (int ks = 0; ks < 2; ks++)
#pragma unroll
      for (int ni = 0; ni < 4; ni++)
#pragma unroll
        for (int mi = 0; mi < 2; mi++)
          sacc[ni][mi] = MFMA(kf[ks][ni], qb[mi][ks], sacc[ni][mi]);

    // P = 2^(S'), no max-subtraction (bounded scores); partial row sums deferred
#pragma unroll
    for (int mi = 0; mi < 2; mi++)
#pragma unroll
      for (int ni = 0; ni < 4; ni++) {
        float p0 = __builtin_amdgcn_exp2f(sacc[ni][mi][0]);
        float p1 = __builtin_amdgcn_exp2f(sacc[ni][mi][1]);
        float p2 = __builtin_amdgcn_exp2f(sacc[ni][mi][2]);
        float p3 = __builtin_amdgcn_exp2f(sacc[ni][mi][3]);
        psum[mi] += (p0 + p1) + (p2 + p3);
        u16* pp = &Ps[w][(mi * 16 + llo) * 64 + ((ni * 16 + lhi * 4) ^ sw)];
        ((unsigned*)pp)[0] = pack_bf2(p0, p1);
        ((unsigned*)pp)[1] = pack_bf2(p2, p3);
      }
    // Ps is per-wave: within-wave lgkmcnt ordering suffices, no barrier

    // O += P V
#pragma unroll
    for (int ks = 0; ks < 2; ks++) {
      const int koff = ks * 32 + lhi * 8;
      bf16x8 pa0 = ld8(&Ps[w][llo * 64 + (koff ^ sw)]);
      bf16x8 pa1 = ld8(&Ps[w][(16 + llo) * 64 + (koff ^ sw)]);
#pragma unroll
      for (int ni = 0; ni < 4; ni++) {
        bf16x8 vb = ld8(&Vt[(ni * 16 + llo) * 64 + (koff ^ sw)]);
        oacc[0][ni] = MFMA(pa0, vb, oacc[0][ni]);
        oacc[1][ni] = MFMA(pa1, vb, oacc[1][ni]);
      }
    }
  }

  // full row sums: reduce across lhi groups, then lane-transpose to output rows
  float rl[2][4];
#pragma unroll
  for (int mi = 0; mi < 2; mi++) {
    psum[mi] += __shfl_xor(psum[mi], 16);
    psum[mi] += __shfl_xor(psum[mi], 32);
#pragma unroll
    for (int r = 0; r < 4; r++) rl[mi][r] = 1.0f / __shfl(psum[mi], lhi * 4 + r);
  }

#pragma unroll
  for (int mi = 0; mi < 2; mi++)
#pragma unroll
    for (int ni = 0; ni < 4; ni++)
#pragma unroll
      for (int r = 0; r < 4; r++) {
        const size_t row = rowb + wq0 + mi * 16 + lhi * 4 + r;
        outp[row * DIMN + h * HD + ni * 16 + llo] = f2bf(oacc[mi][ni][r] * rl[mi][r]);
      }
}

extern "C" void kernel_launch(void* const* d_in, const int* in_sizes, int n_in,
                              void* d_out, int out_size, void* d_ws, size_t ws_size,
                              hipStream_t stream) {
  const float* x = (const float*)d_in[0];
  const float* Wqkv = (const float*)d_in[1];
  const float* bqkv = (const float*)d_in[2];
  const float* Wproj = (const float*)d_in[3];
  const float* bproj = (const float*)d_in[4];
  const float* g1 = (const float*)d_in[5];
  const float* b1 = (const float*)d_in[6];
  const float* g2 = (const float*)d_in[7];
  const float* b2 = (const float*)d_in[8];
  const float* W1 = (const float*)d_in[9];
  const float* bf1 = (const float*)d_in[10];
  const float* W2 = (const float*)d_in[11];
  const float* bf2 = (const float*)d_in[12];
  float* outp = (float*)d_out;

  char* p = (char*)d_ws;
  u16* WqkvT = (u16*)p; p += (size_t)QKVN * DIMN * 2;
  u16* WprojT = (u16*)p; p += (size_t)DIMN * DIMN * 2;
  u16* W1T = (u16*)p; p += (size_t)HID * DIMN * 2;
  u16* W2T = (u16*)p; p += (size_t)DIMN * HID * 2;
  u16* bufX = (u16*)p; p += (size_t)BNROWS * DIMN * 2;  // h1 / attn_out / h2
  u16* big = (u16*)p; p += (size_t)BNROWS * HID * 2;    // qkv then ff1

  // weight transposes (fp32 -> bf16, [K,N] -> [N,K])
  twb_k<<<dim3(QKVN / 32, DIMN / 32), 256, 0, stream>>>(Wqkv, WqkvT, DIMN, QKVN);
  twb_k<<<dim3(DIMN / 32, DIMN / 32), 256, 0, stream>>>(Wproj, WprojT, DIMN, DIMN);
  twb_k<<<dim3(HID / 32, DIMN / 32), 256, 0, stream>>>(W1, W1T, DIMN, HID);
  twb_k<<<dim3(DIMN / 32, HID / 32), 256, 0, stream>>>(W2, W2T, HID, DIMN);

  // LN1
  ln_k<<<BNROWS / 4, 256, 0, stream>>>(x, g1, b1, bufX);
  // QKV GEMM -> big (bf16)
  gemm256_k<1, 0, 0><<<dim3(64, QKVN / 256), 512, 0, stream>>>(bufX, WqkvT, bqkv, nullptr,
                                                               big, QKVN, DIMN);
  // attention -> bufX (bf16)
  attn_k<<<1536, 256, 0, stream>>>(big, bufX);
  // proj GEMM + residual(x) -> d_out (fp32)
  gemm256_k<0, 0, 1><<<dim3(64, DIMN / 256), 512, 0, stream>>>(bufX, WprojT, bproj, x, outp,
                                                               DIMN, DIMN);
  // LN2
  ln_k<<<BNROWS / 4, 256, 0, stream>>>(outp, g2, b2, bufX);
  // FF1 (relu) -> big (bf16)
  gemm256_k<1, 1, 0><<<dim3(64, HID / 256), 512, 0, stream>>>(bufX, W1T, bf1, nullptr, big,
                                                              HID, DIMN);
  // FF2 + residual(d_out) -> d_out (fp32, in place)
  gemm256_k<0, 0, 1><<<dim3(64, DIMN / 256), 512, 0, stream>>>(big, W2T, bf2, outp, outp,
                                                               DIMN, HID);
}

// Round 5
// 462.391 us; speedup vs baseline: 1.6249x; 1.0719x over previous
//
#include <hip/hip_runtime.h>
#include <cstdint>
#include <cstddef>

typedef unsigned short u16;
typedef __bf16 bf16x8 __attribute__((ext_vector_type(8)));
typedef unsigned short u16x8 __attribute__((ext_vector_type(8)));
typedef float f32x4 __attribute__((ext_vector_type(4)));

#define DIMN 768
#define BNROWS 16384
#define NH 12
#define HD 64
#define HID 3072
#define QKVN 2304

__device__ __forceinline__ u16 f2bf(float f) {
  unsigned u = __builtin_bit_cast(unsigned, f);
  u += 0x7fffu + ((u >> 16) & 1u);
  return (u16)(u >> 16);
}

__device__ __forceinline__ bf16x8 ld8(const u16* p) {
  u16x8 v = *reinterpret_cast<const u16x8*>(p);
  return __builtin_bit_cast(bf16x8, v);
}

__device__ __forceinline__ void gload16(const void* g, void* l) {
  __builtin_amdgcn_global_load_lds(
      (const __attribute__((address_space(1))) unsigned int*)g,
      (__attribute__((address_space(3))) unsigned int*)l, 16, 0, 0);
}

#define MFMA(a, b, c) __builtin_amdgcn_mfma_f32_16x16x32_bf16(a, b, c, 0, 0, 0)

// ---------------- weight transpose + cast: W[K,N] f32 -> Wt[N,K] bf16 ----------------
__global__ __launch_bounds__(256) void twb_k(const float* __restrict__ W,
                                             u16* __restrict__ Wt, int K, int N) {
  __shared__ float tile[32][33];
  const int n0 = blockIdx.x * 32, k0 = blockIdx.y * 32;
  const int tx = threadIdx.x & 31, ty = threadIdx.x >> 5;  // ty 0..7
#pragma unroll
  for (int i = 0; i < 4; i++)
    tile[ty + i * 8][tx] = W[(size_t)(k0 + ty + i * 8) * N + n0 + tx];
  __syncthreads();
#pragma unroll
  for (int i = 0; i < 4; i++)
    Wt[(size_t)(n0 + ty + i * 8) * K + k0 + tx] = f2bf(tile[tx][ty + i * 8]);
}

// ---------------- LayerNorm: fp32 row -> bf16 row (one wave per 768-row) ----------------
__global__ __launch_bounds__(256) void ln_k(const float* __restrict__ x,
                                            const float* __restrict__ g,
                                            const float* __restrict__ bta,
                                            u16* __restrict__ outp) {
  const int row = blockIdx.x * 4 + (threadIdx.x >> 6);
  const int lane = threadIdx.x & 63;
  const float4* xr = (const float4*)(x + (size_t)row * DIMN);
  float4 v[3];
  float s = 0.f, ss = 0.f;
#pragma unroll
  for (int c = 0; c < 3; c++) {
    v[c] = xr[c * 64 + lane];
    s += v[c].x + v[c].y + v[c].z + v[c].w;
    ss += v[c].x * v[c].x + v[c].y * v[c].y + v[c].z * v[c].z + v[c].w * v[c].w;
  }
#pragma unroll
  for (int off = 1; off < 64; off <<= 1) {
    s += __shfl_xor(s, off);
    ss += __shfl_xor(ss, off);
  }
  const float mu = s * (1.f / DIMN);
  const float var = ss * (1.f / DIMN) - mu * mu;
  const float rs = rsqrtf(var + 1e-5f);
  u16* orow = outp + (size_t)row * DIMN;
#pragma unroll
  for (int c = 0; c < 3; c++) {
    float4 gv = ((const float4*)g)[c * 64 + lane];
    float4 bv = ((const float4*)bta)[c * 64 + lane];
    ushort4 o;
    o.x = f2bf((v[c].x - mu) * rs * gv.x + bv.x);
    o.y = f2bf((v[c].y - mu) * rs * gv.y + bv.y);
    o.z = f2bf((v[c].z - mu) * rs * gv.z + bv.z);
    o.w = f2bf((v[c].w - mu) * rs * gv.w + bv.w);
    ((ushort4*)orow)[c * 64 + lane] = o;
  }
}

// ---------------- GEMM 256x256, 8 waves, BK=32, 4-slot LDS ring, counted vmcnt ----------
template <int OUT_BF16, int RELU, int RESID>
__global__ __launch_bounds__(512, 2) void gemm256_k(const u16* __restrict__ A,
                                                    const u16* __restrict__ Bt,
                                                    const float* __restrict__ bias,
                                                    const float* __restrict__ resid,
                                                    void* __restrict__ Cout, int N, int K) {
  __shared__ u16 lds[65536];  // 4 slots x (A 16KB + B 16KB) = 128 KiB
  const int tid = threadIdx.x;
  const int m0 = blockIdx.x * 256;
  const int n0 = blockIdx.y * 256;
  const int lane = tid & 63, w = tid >> 6;
  const int wr = w >> 2, wc = w & 3;  // 2 (M) x 4 (N) wave grid, per-wave C = 128x64
  const int lhi = lane >> 4, llo = lane & 15;
  const int NT = K >> 5;

  const int srow = tid >> 2, sc8 = (tid & 3) * 8;
  const u16* aS0 = A + (size_t)(m0 + srow) * K + sc8;
  const u16* aS1 = A + (size_t)(m0 + 128 + srow) * K + sc8;
  const u16* bS0 = Bt + (size_t)(n0 + srow) * K + sc8;
  const u16* bS1 = Bt + (size_t)(n0 + 128 + srow) * K + sc8;

  auto slotBase = [&](int t) -> char* { return (char*)lds + ((size_t)(t & 3) << 15); };
  auto stageA = [&](int t) {
    char* sb = slotBase(t);
    gload16(aS0 + t * 32, sb + tid * 16);
    gload16(aS1 + t * 32, sb + 8192 + tid * 16);
  };
  auto stageB = [&](int t) {
    char* sb = slotBase(t) + 16384;
    gload16(bS0 + t * 32, sb + tid * 16);
    gload16(bS1 + t * 32, sb + 8192 + tid * 16);
  };

  f32x4 acc[8][4] = {};

  stageA(0); stageB(0);
  stageA(1); stageB(1);
  stageA(2); stageB(2);
  asm volatile("s_waitcnt vmcnt(8)" ::: "memory");
  __builtin_amdgcn_s_barrier();

  for (int t = 0; t < NT; ++t) {
    const char* sb = slotBase(t);
    bf16x8 af[4], bfr[4];
#pragma unroll
    for (int ni = 0; ni < 4; ni++)
      bfr[ni] = ld8((const u16*)(sb + 16384 + (wc * 64 + ni * 16 + llo) * 64 + lhi * 16));
#pragma unroll
    for (int mi = 0; mi < 4; mi++)
      af[mi] = ld8((const u16*)(sb + (wr * 128 + mi * 16 + llo) * 64 + lhi * 16));
    if (t + 3 < NT) stageA(t + 3);
    __builtin_amdgcn_s_barrier();
    asm volatile("s_waitcnt lgkmcnt(0)" ::: "memory");
    __builtin_amdgcn_sched_barrier(0);
    __builtin_amdgcn_s_setprio(1);
#pragma unroll
    for (int mi = 0; mi < 4; mi++)
#pragma unroll
      for (int ni = 0; ni < 4; ni++) acc[mi][ni] = MFMA(af[mi], bfr[ni], acc[mi][ni]);
    __builtin_amdgcn_s_setprio(0);
    __builtin_amdgcn_sched_barrier(0);
    __builtin_amdgcn_s_barrier();
#pragma unroll
    for (int mi = 0; mi < 4; mi++)
      af[mi] = ld8((const u16*)(sb + (wr * 128 + 64 + mi * 16 + llo) * 64 + lhi * 16));
    if (t + 3 < NT) stageB(t + 3);
    __builtin_amdgcn_s_barrier();
    asm volatile("s_waitcnt lgkmcnt(0)" ::: "memory");
    __builtin_amdgcn_sched_barrier(0);
    __builtin_amdgcn_s_setprio(1);
#pragma unroll
    for (int mi = 0; mi < 4; mi++)
#pragma unroll
      for (int ni = 0; ni < 4; ni++) acc[4 + mi][ni] = MFMA(af[mi], bfr[ni], acc[4 + mi][ni]);
    __builtin_amdgcn_s_setprio(0);
    __builtin_amdgcn_sched_barrier(0);
    if (t + 3 < NT) {
      asm volatile("s_waitcnt vmcnt(8)" ::: "memory");
    } else if (t + 2 < NT) {
      asm volatile("s_waitcnt vmcnt(4)" ::: "memory");
    } else if (t + 1 < NT) {
      asm volatile("s_waitcnt vmcnt(0)" ::: "memory");
    }
    __builtin_amdgcn_s_barrier();
  }

#pragma unroll
  for (int mi = 0; mi < 8; mi++)
#pragma unroll
    for (int ni = 0; ni < 4; ni++) {
      const int row = m0 + wr * 128 + mi * 16 + lhi * 4;
      const int col = n0 + wc * 64 + ni * 16 + llo;
      const float bsv = bias[col];
#pragma unroll
      for (int rr = 0; rr < 4; rr++) {
        float v = acc[mi][ni][rr] + bsv;
        if (RELU) v = fmaxf(v, 0.0f);
        const size_t idx = (size_t)(row + rr) * N + col;
        if (RESID) v += resid[idx];
        if (OUT_BF16)
          ((u16*)Cout)[idx] = f2bf(v);
        else
          ((float*)Cout)[idx] = v;
      }
    }
}

// ---------------- fused attention (pipelined) ----------------
// QBLK=128, 4 waves x 32 q-rows. K staged in LDS via global_load_lds with pre-swizzled
// source (dbuf); V reg-loaded -> transposed swizzled LDS (dbuf); Ps per-wave LDS.
// Swapped QK^T, no-max softmax (bounded scores, prescaled by 768^-0.5*log2e).
// Pipeline ledger (2 raw barriers/tile):
//   mid-barrier: after QK^T MFMAs (all waves' ds_reads of Ks[t&1] consumed) -> safe to
//     issue stageK(t+2) into Ks[t&1]. lgkmcnt(0)+sched_barrier fence both sides.
//   end-barrier: after vmcnt(2) (drains K_lds(t+1)+V(t+1); keeps K_lds(t+2) in flight)
//     and Vt[(t+1)&1] writes -> K(t+1)/Vt(t+1) visible for next tile. Vt WAR: writers
//     of Vt[(t+1)&1] are past mid-barrier(t), which implies all PV(t-1) reads done.
__device__ __forceinline__ bf16x8 ldscale8(const u16* p, float c) {
  u16x8 v = *reinterpret_cast<const u16x8*>(p);
  bf16x8 r;
#pragma unroll
  for (int j = 0; j < 8; j++) {
    float f = __builtin_bit_cast(float, (unsigned)v[j] << 16) * c;
    r[j] = (__bf16)f;
  }
  return r;
}

__device__ __forceinline__ unsigned pack_bf2(float a, float b) {
  unsigned ua = (unsigned)__builtin_bit_cast(u16, (__bf16)a);
  unsigned ub = (unsigned)__builtin_bit_cast(u16, (__bf16)b);
  return ua | (ub << 16);
}

__global__ __launch_bounds__(256) void attn_k(const u16* __restrict__ qkv,
                                              u16* __restrict__ outp) {
  __shared__ u16 Ks[2][64 * 64];  // K[kv][d], 16B-unit u swizzled: holds G-unit u^(kv&7)
  __shared__ u16 Vt[2][64 * 64];  // V^T[d][kv], kv swizzled by ((d&7)*8)
  __shared__ u16 Ps[4][32 * 64];  // per-wave P[q][kv], kv swizzled by ((q&7)*8)

  const int tid = threadIdx.x;
  const int f = blockIdx.x;                  // 0..1535
  const int bh = (f & 7) | ((f >> 6) << 3);  // all 8 q-tiles of one bh on one XCD
  const int qt = (f >> 3) & 7;
  const int b = bh / NH, h = bh - b * NH;
  const int lane = tid & 63, w = tid >> 6;
  const int lhi = lane >> 4, llo = lane & 15;
  const size_t rowb = (size_t)b * 1024;
  const int wq0 = qt * 128 + w * 32;
  const float SC = 0.052059750f;  // 768^-0.5 * log2(e)

  // Q fragments (B-operand of swapped QK^T), prescaled, loop-invariant
  bf16x8 qb[2][2];
#pragma unroll
  for (int mi = 0; mi < 2; mi++) {
    const u16* qrow = qkv + (rowb + wq0 + mi * 16 + llo) * QKVN + h * HD;
    qb[mi][0] = ldscale8(qrow + lhi * 8, SC);
    qb[mi][1] = ldscale8(qrow + 32 + lhi * 8, SC);
  }

  const u16* kbase = qkv + rowb * QKVN + DIMN + h * HD;
  const u16* vbase = qkv + rowb * QKVN + 2 * DIMN + h * HD;
  const int vc8 = w * 8;
  const int sw = (llo & 7) * 8;
  const int rsw = llo & 7;

  // K staging: thread stages LDS slots tid*16 and 4096+tid*16 (rows srow, srow+32).
  // Source pre-swizzled: LDS[row][u] <- G[row][u ^ (row&7)]; (row+32)&7 == row&7.
  const int srow = tid >> 3, su = tid & 7;
  const u16* ksrc = kbase + (size_t)srow * QKVN + (su ^ (srow & 7)) * 8;

  auto stageK = [&](int kt, int buf) {
    const u16* s0 = ksrc + (size_t)kt * 64 * QKVN;
    gload16(s0, (char*)&Ks[buf][0] + tid * 16);
    gload16(s0 + (size_t)32 * QKVN, (char*)&Ks[buf][0] + 4096 + tid * 16);
  };
  auto loadV = [&](int kt, u16x8& a, u16x8& c) {
    const u16* vr = vbase + (size_t)(kt * 64 + lane) * QKVN + vc8;
    a = *reinterpret_cast<const u16x8*>(vr);
    c = *reinterpret_cast<const u16x8*>(vr + 32);
  };
  auto writeV = [&](int buf, u16x8 a, u16x8 c) {
#pragma unroll
    for (int j = 0; j < 8; j++) {
      Vt[buf][(vc8 + j) * 64 + (lane ^ (j * 8))] = a[j];
      Vt[buf][(vc8 + 32 + j) * 64 + (lane ^ (j * 8))] = c[j];
    }
  };

  u16x8 v0, v1, nv0, nv1;

  // prologue: K(0), V(0), K(1) in flight; land K0+V0, publish Vt0
  stageK(0, 0);
  loadV(0, v0, v1);
  stageK(1, 1);
  asm volatile("s_waitcnt vmcnt(2)" ::: "memory");
  writeV(0, v0, v1);
  asm volatile("s_waitcnt lgkmcnt(0)" ::: "memory");
  __builtin_amdgcn_s_barrier();
  __builtin_amdgcn_sched_barrier(0);

  float psum[2] = {0.f, 0.f};
  f32x4 oacc[2][4] = {};

  for (int t = 0; t < 16; t++) {
    if (t < 15) loadV(t + 1, nv0, nv1);

    // ---- S^T = K Q^T from Ks[t&1] (swizzled ds_read_b128, 2-way free) ----
    const u16* kB = &Ks[t & 1][0];
    f32x4 sacc[4][2] = {};
#pragma unroll
    for (int ks = 0; ks < 2; ks++)
#pragma unroll
      for (int ni = 0; ni < 4; ni++) {
        bf16x8 kf = ld8(&kB[(ni * 16 + llo) * 64 + (((ks * 4 + lhi) ^ rsw) * 8)]);
#pragma unroll
        for (int mi = 0; mi < 2; mi++) sacc[ni][mi] = MFMA(kf, qb[mi][ks], sacc[ni][mi]);
      }

    asm volatile("s_waitcnt lgkmcnt(0)" ::: "memory");
    __builtin_amdgcn_s_barrier();  // all waves done reading Ks[t&1]
    __builtin_amdgcn_sched_barrier(0);
    if (t + 2 < 16) stageK(t + 2, t & 1);

    // ---- P = 2^(S'), deferred row sums ----
#pragma unroll
    for (int mi = 0; mi < 2; mi++)
#pragma unroll
      for (int ni = 0; ni < 4; ni++) {
        float p0 = __builtin_amdgcn_exp2f(sacc[ni][mi][0]);
        float p1 = __builtin_amdgcn_exp2f(sacc[ni][mi][1]);
        float p2 = __builtin_amdgcn_exp2f(sacc[ni][mi][2]);
        float p3 = __builtin_amdgcn_exp2f(sacc[ni][mi][3]);
        psum[mi] += (p0 + p1) + (p2 + p3);
        u16* pp = &Ps[w][(mi * 16 + llo) * 64 + ((ni * 16 + lhi * 4) ^ sw)];
        uint2 pw;
        pw.x = pack_bf2(p0, p1);
        pw.y = pack_bf2(p2, p3);
        *reinterpret_cast<uint2*>(pp) = pw;  // ds_write_b64
      }
    // Ps per-wave: within-wave lgkm ordering suffices

    // ---- O += P V from Vt[t&1] ----
#pragma unroll
    for (int ks = 0; ks < 2; ks++) {
      const int koff = ks * 32 + lhi * 8;
      bf16x8 pa0 = ld8(&Ps[w][llo * 64 + (koff ^ sw)]);
      bf16x8 pa1 = ld8(&Ps[w][(16 + llo) * 64 + (koff ^ sw)]);
#pragma unroll
      for (int ni = 0; ni < 4; ni++) {
        bf16x8 vb = ld8(&Vt[t & 1][(ni * 16 + llo) * 64 + (koff ^ sw)]);
        oacc[0][ni] = MFMA(pa0, vb, oacc[0][ni]);
        oacc[1][ni] = MFMA(pa1, vb, oacc[1][ni]);
      }
    }

    if (t < 15) {
      if (t + 2 < 16) {
        asm volatile("s_waitcnt vmcnt(2)" ::: "memory");  // K(t+1)+V(t+1) landed; K(t+2) in flight
      } else {
        asm volatile("s_waitcnt vmcnt(0)" ::: "memory");  // tail: no K(t+2) issued
      }
      writeV((t + 1) & 1, nv0, nv1);
      v0 = nv0; v1 = nv1;
      asm volatile("s_waitcnt lgkmcnt(0)" ::: "memory");
      __builtin_amdgcn_s_barrier();  // K(t+1), Vt(t+1) visible
      __builtin_amdgcn_sched_barrier(0);
    }
  }

  // full row sums: reduce across lhi groups, then lane-transpose to output rows
  float rl[2][4];
#pragma unroll
  for (int mi = 0; mi < 2; mi++) {
    psum[mi] += __shfl_xor(psum[mi], 16);
    psum[mi] += __shfl_xor(psum[mi], 32);
#pragma unroll
    for (int r = 0; r < 4; r++) rl[mi][r] = 1.0f / __shfl(psum[mi], lhi * 4 + r);
  }

#pragma unroll
  for (int mi = 0; mi < 2; mi++)
#pragma unroll
    for (int ni = 0; ni < 4; ni++)
#pragma unroll
      for (int r = 0; r < 4; r++) {
        const size_t row = rowb + wq0 + mi * 16 + lhi * 4 + r;
        outp[row * DIMN + h * HD + ni * 16 + llo] = f2bf(oacc[mi][ni][r] * rl[mi][r]);
      }
}

extern "C" void kernel_launch(void* const* d_in, const int* in_sizes, int n_in,
                              void* d_out, int out_size, void* d_ws, size_t ws_size,
                              hipStream_t stream) {
  const float* x = (const float*)d_in[0];
  const float* Wqkv = (const float*)d_in[1];
  const float* bqkv = (const float*)d_in[2];
  const float* Wproj = (const float*)d_in[3];
  const float* bproj = (const float*)d_in[4];
  const float* g1 = (const float*)d_in[5];
  const float* b1 = (const float*)d_in[6];
  const float* g2 = (const float*)d_in[7];
  const float* b2 = (const float*)d_in[8];
  const float* W1 = (const float*)d_in[9];
  const float* bf1 = (const float*)d_in[10];
  const float* W2 = (const float*)d_in[11];
  const float* bf2 = (const float*)d_in[12];
  float* outp = (float*)d_out;

  char* p = (char*)d_ws;
  u16* WqkvT = (u16*)p; p += (size_t)QKVN * DIMN * 2;
  u16* WprojT = (u16*)p; p += (size_t)DIMN * DIMN * 2;
  u16* W1T = (u16*)p; p += (size_t)HID * DIMN * 2;
  u16* W2T = (u16*)p; p += (size_t)DIMN * HID * 2;
  u16* bufX = (u16*)p; p += (size_t)BNROWS * DIMN * 2;  // h1 / attn_out / h2
  u16* big = (u16*)p; p += (size_t)BNROWS * HID * 2;    // qkv then ff1

  twb_k<<<dim3(QKVN / 32, DIMN / 32), 256, 0, stream>>>(Wqkv, WqkvT, DIMN, QKVN);
  twb_k<<<dim3(DIMN / 32, DIMN / 32), 256, 0, stream>>>(Wproj, WprojT, DIMN, DIMN);
  twb_k<<<dim3(HID / 32, DIMN / 32), 256, 0, stream>>>(W1, W1T, DIMN, HID);
  twb_k<<<dim3(DIMN / 32, HID / 32), 256, 0, stream>>>(W2, W2T, HID, DIMN);

  ln_k<<<BNROWS / 4, 256, 0, stream>>>(x, g1, b1, bufX);
  gemm256_k<1, 0, 0><<<dim3(64, QKVN / 256), 512, 0, stream>>>(bufX, WqkvT, bqkv, nullptr,
                                                               big, QKVN, DIMN);
  attn_k<<<1536, 256, 0, stream>>>(big, bufX);
  gemm256_k<0, 0, 1><<<dim3(64, DIMN / 256), 512, 0, stream>>>(bufX, WprojT, bproj, x, outp,
                                                               DIMN, DIMN);
  ln_k<<<BNROWS / 4, 256, 0, stream>>>(outp, g2, b2, bufX);
  gemm256_k<1, 1, 0><<<dim3(64, HID / 256), 512, 0, stream>>>(bufX, W1T, bf1, nullptr, big,
                                                              HID, DIMN);
  gemm256_k<0, 0, 1><<<dim3(64, DIMN / 256), 512, 0, stream>>>(big, W2T, bf2, outp, outp,
                                                               DIMN, HID);
}

// Round 6
// 455.792 us; speedup vs baseline: 1.6485x; 1.0145x over previous
//
#include <hip/hip_runtime.h>
#include <cstdint>
#include <cstddef>

typedef unsigned short u16;
typedef __bf16 bf16x8 __attribute__((ext_vector_type(8)));
typedef unsigned short u16x8 __attribute__((ext_vector_type(8)));
typedef float f32x4 __attribute__((ext_vector_type(4)));

#define DIMN 768
#define BNROWS 16384
#define NH 12
#define HD 64
#define HID 3072
#define QKVN 2304

__device__ __forceinline__ u16 f2bf(float f) {
  unsigned u = __builtin_bit_cast(unsigned, f);
  u += 0x7fffu + ((u >> 16) & 1u);
  return (u16)(u >> 16);
}

__device__ __forceinline__ bf16x8 ld8(const u16* p) {
  u16x8 v = *reinterpret_cast<const u16x8*>(p);
  return __builtin_bit_cast(bf16x8, v);
}

__device__ __forceinline__ void gload16(const void* g, void* l) {
  __builtin_amdgcn_global_load_lds(
      (const __attribute__((address_space(1))) unsigned int*)g,
      (__attribute__((address_space(3))) unsigned int*)l, 16, 0, 0);
}

#define MFMA(a, b, c) __builtin_amdgcn_mfma_f32_16x16x32_bf16(a, b, c, 0, 0, 0)

// ---------------- weight transpose + cast: W[K,N] f32 -> Wt[N,K] bf16 ----------------
__global__ __launch_bounds__(256) void twb_k(const float* __restrict__ W,
                                             u16* __restrict__ Wt, int K, int N) {
  __shared__ float tile[32][33];
  const int n0 = blockIdx.x * 32, k0 = blockIdx.y * 32;
  const int tx = threadIdx.x & 31, ty = threadIdx.x >> 5;  // ty 0..7
#pragma unroll
  for (int i = 0; i < 4; i++)
    tile[ty + i * 8][tx] = W[(size_t)(k0 + ty + i * 8) * N + n0 + tx];
  __syncthreads();
#pragma unroll
  for (int i = 0; i < 4; i++)
    Wt[(size_t)(n0 + ty + i * 8) * K + k0 + tx] = f2bf(tile[tx][ty + i * 8]);
}

// ---------------- LayerNorm: fp32 row -> bf16 row (one wave per 768-row) ----------------
__global__ __launch_bounds__(256) void ln_k(const float* __restrict__ x,
                                            const float* __restrict__ g,
                                            const float* __restrict__ bta,
                                            u16* __restrict__ outp) {
  const int row = blockIdx.x * 4 + (threadIdx.x >> 6);
  const int lane = threadIdx.x & 63;
  const float4* xr = (const float4*)(x + (size_t)row * DIMN);
  float4 v[3];
  float s = 0.f, ss = 0.f;
#pragma unroll
  for (int c = 0; c < 3; c++) {
    v[c] = xr[c * 64 + lane];
    s += v[c].x + v[c].y + v[c].z + v[c].w;
    ss += v[c].x * v[c].x + v[c].y * v[c].y + v[c].z * v[c].z + v[c].w * v[c].w;
  }
#pragma unroll
  for (int off = 1; off < 64; off <<= 1) {
    s += __shfl_xor(s, off);
    ss += __shfl_xor(ss, off);
  }
  const float mu = s * (1.f / DIMN);
  const float var = ss * (1.f / DIMN) - mu * mu;
  const float rs = rsqrtf(var + 1e-5f);
  u16* orow = outp + (size_t)row * DIMN;
#pragma unroll
  for (int c = 0; c < 3; c++) {
    float4 gv = ((const float4*)g)[c * 64 + lane];
    float4 bv = ((const float4*)bta)[c * 64 + lane];
    ushort4 o;
    o.x = f2bf((v[c].x - mu) * rs * gv.x + bv.x);
    o.y = f2bf((v[c].y - mu) * rs * gv.y + bv.y);
    o.z = f2bf((v[c].z - mu) * rs * gv.z + bv.z);
    o.w = f2bf((v[c].w - mu) * rs * gv.w + bv.w);
    ((ushort4*)orow)[c * 64 + lane] = o;
  }
}

// ---------------- GEMM 256x256, 8 waves, BK=32, 4-slot LDS ring, counted vmcnt ----------
// Used for QKV (N=2304) and FF1 (N=3072) where the grid fills the CUs.
template <int OUT_BF16, int RELU, int RESID>
__global__ __launch_bounds__(512, 2) void gemm256_k(const u16* __restrict__ A,
                                                    const u16* __restrict__ Bt,
                                                    const float* __restrict__ bias,
                                                    const float* __restrict__ resid,
                                                    void* __restrict__ Cout, int N, int K) {
  __shared__ u16 lds[65536];  // 4 slots x (A 16KB + B 16KB) = 128 KiB
  const int tid = threadIdx.x;
  const int m0 = blockIdx.x * 256;
  const int n0 = blockIdx.y * 256;
  const int lane = tid & 63, w = tid >> 6;
  const int wr = w >> 2, wc = w & 3;  // 2 (M) x 4 (N) wave grid, per-wave C = 128x64
  const int lhi = lane >> 4, llo = lane & 15;
  const int NT = K >> 5;

  const int srow = tid >> 2, sc8 = (tid & 3) * 8;
  const u16* aS0 = A + (size_t)(m0 + srow) * K + sc8;
  const u16* aS1 = A + (size_t)(m0 + 128 + srow) * K + sc8;
  const u16* bS0 = Bt + (size_t)(n0 + srow) * K + sc8;
  const u16* bS1 = Bt + (size_t)(n0 + 128 + srow) * K + sc8;

  auto slotBase = [&](int t) -> char* { return (char*)lds + ((size_t)(t & 3) << 15); };
  auto stageA = [&](int t) {
    char* sb = slotBase(t);
    gload16(aS0 + t * 32, sb + tid * 16);
    gload16(aS1 + t * 32, sb + 8192 + tid * 16);
  };
  auto stageB = [&](int t) {
    char* sb = slotBase(t) + 16384;
    gload16(bS0 + t * 32, sb + tid * 16);
    gload16(bS1 + t * 32, sb + 8192 + tid * 16);
  };

  f32x4 acc[8][4] = {};

  stageA(0); stageB(0);
  stageA(1); stageB(1);
  stageA(2); stageB(2);
  asm volatile("s_waitcnt vmcnt(8)" ::: "memory");
  __builtin_amdgcn_s_barrier();

  for (int t = 0; t < NT; ++t) {
    const char* sb = slotBase(t);
    bf16x8 af[4], bfr[4];
#pragma unroll
    for (int ni = 0; ni < 4; ni++)
      bfr[ni] = ld8((const u16*)(sb + 16384 + (wc * 64 + ni * 16 + llo) * 64 + lhi * 16));
#pragma unroll
    for (int mi = 0; mi < 4; mi++)
      af[mi] = ld8((const u16*)(sb + (wr * 128 + mi * 16 + llo) * 64 + lhi * 16));
    if (t + 3 < NT) stageA(t + 3);
    __builtin_amdgcn_s_barrier();
    asm volatile("s_waitcnt lgkmcnt(0)" ::: "memory");
    __builtin_amdgcn_sched_barrier(0);
    __builtin_amdgcn_s_setprio(1);
#pragma unroll
    for (int mi = 0; mi < 4; mi++)
#pragma unroll
      for (int ni = 0; ni < 4; ni++) acc[mi][ni] = MFMA(af[mi], bfr[ni], acc[mi][ni]);
    __builtin_amdgcn_s_setprio(0);
    __builtin_amdgcn_sched_barrier(0);
    __builtin_amdgcn_s_barrier();
#pragma unroll
    for (int mi = 0; mi < 4; mi++)
      af[mi] = ld8((const u16*)(sb + (wr * 128 + 64 + mi * 16 + llo) * 64 + lhi * 16));
    if (t + 3 < NT) stageB(t + 3);
    __builtin_amdgcn_s_barrier();
    asm volatile("s_waitcnt lgkmcnt(0)" ::: "memory");
    __builtin_amdgcn_sched_barrier(0);
    __builtin_amdgcn_s_setprio(1);
#pragma unroll
    for (int mi = 0; mi < 4; mi++)
#pragma unroll
      for (int ni = 0; ni < 4; ni++) acc[4 + mi][ni] = MFMA(af[mi], bfr[ni], acc[4 + mi][ni]);
    __builtin_amdgcn_s_setprio(0);
    __builtin_amdgcn_sched_barrier(0);
    if (t + 3 < NT) {
      asm volatile("s_waitcnt vmcnt(8)" ::: "memory");
    } else if (t + 2 < NT) {
      asm volatile("s_waitcnt vmcnt(4)" ::: "memory");
    } else if (t + 1 < NT) {
      asm volatile("s_waitcnt vmcnt(0)" ::: "memory");
    }
    __builtin_amdgcn_s_barrier();
  }

#pragma unroll
  for (int mi = 0; mi < 8; mi++)
#pragma unroll
    for (int ni = 0; ni < 4; ni++) {
      const int row = m0 + wr * 128 + mi * 16 + lhi * 4;
      const int col = n0 + wc * 64 + ni * 16 + llo;
      const float bsv = bias[col];
#pragma unroll
      for (int rr = 0; rr < 4; rr++) {
        float v = acc[mi][ni][rr] + bsv;
        if (RELU) v = fmaxf(v, 0.0f);
        const size_t idx = (size_t)(row + rr) * N + col;
        if (RESID) v += resid[idx];
        if (OUT_BF16)
          ((u16*)Cout)[idx] = f2bf(v);
        else
          ((float*)Cout)[idx] = v;
      }
    }
}

// ---------------- GEMM 256x128, 4 waves, BK=32, 3-slot ring, 2 blocks/CU --------------
// For N=768 ops (proj, FF2): grid 64x6=384 blocks fills all CUs; 72 KiB LDS -> 2 blocks
// co-resident so epilogue/prologue/barrier-skew of one block hides under the other.
// Staging: 6 gload16/thread/tile (A 4, B 2); in-flight 2 tiles -> boundary vmcnt(6).
// WAR: stage(t+2) targets slot (t-1)%3 whose reads finished before t-1's final barrier.
template <int OUT_BF16, int RELU, int RESID>
__global__ __launch_bounds__(256, 2) void gemmP_k(const u16* __restrict__ A,
                                                  const u16* __restrict__ Bt,
                                                  const float* __restrict__ bias,
                                                  const float* __restrict__ resid,
                                                  void* __restrict__ Cout, int N, int K) {
  __shared__ u16 lds[3 * 12288];  // 3 slots x (A[256][32] 16KB + B[128][32] 8KB)
  const int tid = threadIdx.x;
  const int m0 = blockIdx.x * 256;
  const int n0 = blockIdx.y * 128;
  const int lane = tid & 63, w = tid >> 6;
  const int wr = w >> 1, wc = w & 1;  // 2 (M) x 2 (N) waves, per-wave C = 128x64
  const int lhi = lane >> 4, llo = lane & 15;
  const int NT = K >> 5;

  const int crow = tid >> 2, kc8 = (tid & 3) * 8;
  const u16* aS = A + (size_t)(m0 + crow) * K + kc8;   // + 64*s rows
  const u16* bS = Bt + (size_t)(n0 + crow) * K + kc8;  // + 64*s rows (s<2)
  const size_t a64 = (size_t)64 * K;

  auto slotBase = [&](int t) -> char* { return (char*)lds + (t % 3) * 24576; };
  auto stage1 = [&](int t) {  // A rows 0..127, B rows 0..63
    char* sb = slotBase(t);
    gload16(aS + t * 32, sb + tid * 16);
    gload16(aS + a64 + t * 32, sb + 4096 + tid * 16);
    gload16(bS + t * 32, sb + 16384 + tid * 16);
  };
  auto stage2 = [&](int t) {  // A rows 128..255, B rows 64..127
    char* sb = slotBase(t);
    gload16(aS + 2 * a64 + t * 32, sb + 8192 + tid * 16);
    gload16(aS + 3 * a64 + t * 32, sb + 12288 + tid * 16);
    gload16(bS + a64 + t * 32, sb + 16384 + 4096 + tid * 16);
  };

  f32x4 acc[8][4] = {};

  stage1(0); stage2(0);
  stage1(1); stage2(1);
  asm volatile("s_waitcnt vmcnt(6)" ::: "memory");
  __builtin_amdgcn_s_barrier();

  for (int t = 0; t < NT; ++t) {
    const char* sb = slotBase(t);
    bf16x8 af[4], bfr[4];
#pragma unroll
    for (int ni = 0; ni < 4; ni++)
      bfr[ni] = ld8((const u16*)(sb + 16384 + (wc * 64 + ni * 16 + llo) * 64 + lhi * 16));
#pragma unroll
    for (int mi = 0; mi < 4; mi++)
      af[mi] = ld8((const u16*)(sb + (wr * 128 + mi * 16 + llo) * 64 + lhi * 16));
    if (t + 2 < NT) stage1(t + 2);
    __builtin_amdgcn_s_barrier();
    asm volatile("s_waitcnt lgkmcnt(0)" ::: "memory");
    __builtin_amdgcn_sched_barrier(0);
    __builtin_amdgcn_s_setprio(1);
#pragma unroll
    for (int mi = 0; mi < 4; mi++)
#pragma unroll
      for (int ni = 0; ni < 4; ni++) acc[mi][ni] = MFMA(af[mi], bfr[ni], acc[mi][ni]);
    __builtin_amdgcn_s_setprio(0);
    __builtin_amdgcn_sched_barrier(0);
    __builtin_amdgcn_s_barrier();
#pragma unroll
    for (int mi = 0; mi < 4; mi++)
      af[mi] = ld8((const u16*)(sb + (wr * 128 + 64 + mi * 16 + llo) * 64 + lhi * 16));
    if (t + 2 < NT) stage2(t + 2);
    __builtin_amdgcn_s_barrier();
    asm volatile("s_waitcnt lgkmcnt(0)" ::: "memory");
    __builtin_amdgcn_sched_barrier(0);
    __builtin_amdgcn_s_setprio(1);
#pragma unroll
    for (int mi = 0; mi < 4; mi++)
#pragma unroll
      for (int ni = 0; ni < 4; ni++) acc[4 + mi][ni] = MFMA(af[mi], bfr[ni], acc[4 + mi][ni]);
    __builtin_amdgcn_s_setprio(0);
    __builtin_amdgcn_sched_barrier(0);
    if (t + 2 < NT) {
      asm volatile("s_waitcnt vmcnt(6)" ::: "memory");
    } else if (t + 1 < NT) {
      asm volatile("s_waitcnt vmcnt(0)" ::: "memory");
    }
    __builtin_amdgcn_s_barrier();
  }

#pragma unroll
  for (int mi = 0; mi < 8; mi++)
#pragma unroll
    for (int ni = 0; ni < 4; ni++) {
      const int row = m0 + wr * 128 + mi * 16 + lhi * 4;
      const int col = n0 + wc * 64 + ni * 16 + llo;
      const float bsv = bias[col];
#pragma unroll
      for (int rr = 0; rr < 4; rr++) {
        float v = acc[mi][ni][rr] + bsv;
        if (RELU) v = fmaxf(v, 0.0f);
        const size_t idx = (size_t)(row + rr) * N + col;
        if (RESID) v += resid[idx];
        if (OUT_BF16)
          ((u16*)Cout)[idx] = f2bf(v);
        else
          ((float*)Cout)[idx] = v;
      }
    }
}

// ---------------- fused attention (pipelined) ----------------
__device__ __forceinline__ bf16x8 ldscale8(const u16* p, float c) {
  u16x8 v = *reinterpret_cast<const u16x8*>(p);
  bf16x8 r;
#pragma unroll
  for (int j = 0; j < 8; j++) {
    float f = __builtin_bit_cast(float, (unsigned)v[j] << 16) * c;
    r[j] = (__bf16)f;
  }
  return r;
}

__device__ __forceinline__ unsigned pack_bf2(float a, float b) {
  unsigned ua = (unsigned)__builtin_bit_cast(u16, (__bf16)a);
  unsigned ub = (unsigned)__builtin_bit_cast(u16, (__bf16)b);
  return ua | (ub << 16);
}

__global__ __launch_bounds__(256) void attn_k(const u16* __restrict__ qkv,
                                              u16* __restrict__ outp) {
  __shared__ u16 Ks[2][64 * 64];  // K[kv][d], 16B-unit u swizzled: holds G-unit u^(kv&7)
  __shared__ u16 Vt[2][64 * 64];  // V^T[d][kv], kv swizzled by ((d&7)*8)
  __shared__ u16 Ps[4][32 * 64];  // per-wave P[q][kv], kv swizzled by ((q&7)*8)

  const int tid = threadIdx.x;
  const int f = blockIdx.x;                  // 0..1535
  const int bh = (f & 7) | ((f >> 6) << 3);  // all 8 q-tiles of one bh on one XCD
  const int qt = (f >> 3) & 7;
  const int b = bh / NH, h = bh - b * NH;
  const int lane = tid & 63, w = tid >> 6;
  const int lhi = lane >> 4, llo = lane & 15;
  const size_t rowb = (size_t)b * 1024;
  const int wq0 = qt * 128 + w * 32;
  const float SC = 0.052059750f;  // 768^-0.5 * log2(e)

  bf16x8 qb[2][2];
#pragma unroll
  for (int mi = 0; mi < 2; mi++) {
    const u16* qrow = qkv + (rowb + wq0 + mi * 16 + llo) * QKVN + h * HD;
    qb[mi][0] = ldscale8(qrow + lhi * 8, SC);
    qb[mi][1] = ldscale8(qrow + 32 + lhi * 8, SC);
  }

  const u16* kbase = qkv + rowb * QKVN + DIMN + h * HD;
  const u16* vbase = qkv + rowb * QKVN + 2 * DIMN + h * HD;
  const int vc8 = w * 8;
  const int sw = (llo & 7) * 8;
  const int rsw = llo & 7;

  const int srow = tid >> 3, su = tid & 7;
  const u16* ksrc = kbase + (size_t)srow * QKVN + (su ^ (srow & 7)) * 8;

  auto stageK = [&](int kt, int buf) {
    const u16* s0 = ksrc + (size_t)kt * 64 * QKVN;
    gload16(s0, (char*)&Ks[buf][0] + tid * 16);
    gload16(s0 + (size_t)32 * QKVN, (char*)&Ks[buf][0] + 4096 + tid * 16);
  };
  auto loadV = [&](int kt, u16x8& a, u16x8& c) {
    const u16* vr = vbase + (size_t)(kt * 64 + lane) * QKVN + vc8;
    a = *reinterpret_cast<const u16x8*>(vr);
    c = *reinterpret_cast<const u16x8*>(vr + 32);
  };
  auto writeV = [&](int buf, u16x8 a, u16x8 c) {
#pragma unroll
    for (int j = 0; j < 8; j++) {
      Vt[buf][(vc8 + j) * 64 + (lane ^ (j * 8))] = a[j];
      Vt[buf][(vc8 + 32 + j) * 64 + (lane ^ (j * 8))] = c[j];
    }
  };

  u16x8 v0, v1, nv0, nv1;

  stageK(0, 0);
  loadV(0, v0, v1);
  stageK(1, 1);
  asm volatile("s_waitcnt vmcnt(2)" ::: "memory");
  writeV(0, v0, v1);
  asm volatile("s_waitcnt lgkmcnt(0)" ::: "memory");
  __builtin_amdgcn_s_barrier();
  __builtin_amdgcn_sched_barrier(0);

  float psum[2] = {0.f, 0.f};
  f32x4 oacc[2][4] = {};

  for (int t = 0; t < 16; t++) {
    if (t < 15) loadV(t + 1, nv0, nv1);

    const u16* kB = &Ks[t & 1][0];
    f32x4 sacc[4][2] = {};
#pragma unroll
    for (int ks = 0; ks < 2; ks++)
#pragma unroll
      for (int ni = 0; ni < 4; ni++) {
        bf16x8 kf = ld8(&kB[(ni * 16 + llo) * 64 + (((ks * 4 + lhi) ^ rsw) * 8)]);
#pragma unroll
        for (int mi = 0; mi < 2; mi++) sacc[ni][mi] = MFMA(kf, qb[mi][ks], sacc[ni][mi]);
      }

    asm volatile("s_waitcnt lgkmcnt(0)" ::: "memory");
    __builtin_amdgcn_s_barrier();  // all waves done reading Ks[t&1]
    __builtin_amdgcn_sched_barrier(0);
    if (t + 2 < 16) stageK(t + 2, t & 1);

#pragma unroll
    for (int mi = 0; mi < 2; mi++)
#pragma unroll
      for (int ni = 0; ni < 4; ni++) {
        float p0 = __builtin_amdgcn_exp2f(sacc[ni][mi][0]);
        float p1 = __builtin_amdgcn_exp2f(sacc[ni][mi][1]);
        float p2 = __builtin_amdgcn_exp2f(sacc[ni][mi][2]);
        float p3 = __builtin_amdgcn_exp2f(sacc[ni][mi][3]);
        psum[mi] += (p0 + p1) + (p2 + p3);
        u16* pp = &Ps[w][(mi * 16 + llo) * 64 + ((ni * 16 + lhi * 4) ^ sw)];
        uint2 pw;
        pw.x = pack_bf2(p0, p1);
        pw.y = pack_bf2(p2, p3);
        *reinterpret_cast<uint2*>(pp) = pw;  // ds_write_b64
      }

#pragma unroll
    for (int ks = 0; ks < 2; ks++) {
      const int koff = ks * 32 + lhi * 8;
      bf16x8 pa0 = ld8(&Ps[w][llo * 64 + (koff ^ sw)]);
      bf16x8 pa1 = ld8(&Ps[w][(16 + llo) * 64 + (koff ^ sw)]);
#pragma unroll
      for (int ni = 0; ni < 4; ni++) {
        bf16x8 vb = ld8(&Vt[t & 1][(ni * 16 + llo) * 64 + (koff ^ sw)]);
        oacc[0][ni] = MFMA(pa0, vb, oacc[0][ni]);
        oacc[1][ni] = MFMA(pa1, vb, oacc[1][ni]);
      }
    }

    if (t < 15) {
      if (t + 2 < 16) {
        asm volatile("s_waitcnt vmcnt(2)" ::: "memory");
      } else {
        asm volatile("s_waitcnt vmcnt(0)" ::: "memory");
      }
      writeV((t + 1) & 1, nv0, nv1);
      v0 = nv0; v1 = nv1;
      asm volatile("s_waitcnt lgkmcnt(0)" ::: "memory");
      __builtin_amdgcn_s_barrier();
      __builtin_amdgcn_sched_barrier(0);
    }
  }

  float rl[2][4];
#pragma unroll
  for (int mi = 0; mi < 2; mi++) {
    psum[mi] += __shfl_xor(psum[mi], 16);
    psum[mi] += __shfl_xor(psum[mi], 32);
#pragma unroll
    for (int r = 0; r < 4; r++) rl[mi][r] = 1.0f / __shfl(psum[mi], lhi * 4 + r);
  }

#pragma unroll
  for (int mi = 0; mi < 2; mi++)
#pragma unroll
    for (int ni = 0; ni < 4; ni++)
#pragma unroll
      for (int r = 0; r < 4; r++) {
        const size_t row = rowb + wq0 + mi * 16 + lhi * 4 + r;
        outp[row * DIMN + h * HD + ni * 16 + llo] = f2bf(oacc[mi][ni][r] * rl[mi][r]);
      }
}

extern "C" void kernel_launch(void* const* d_in, const int* in_sizes, int n_in,
                              void* d_out, int out_size, void* d_ws, size_t ws_size,
                              hipStream_t stream) {
  const float* x = (const float*)d_in[0];
  const float* Wqkv = (const float*)d_in[1];
  const float* bqkv = (const float*)d_in[2];
  const float* Wproj = (const float*)d_in[3];
  const float* bproj = (const float*)d_in[4];
  const float* g1 = (const float*)d_in[5];
  const float* b1 = (const float*)d_in[6];
  const float* g2 = (const float*)d_in[7];
  const float* b2 = (const float*)d_in[8];
  const float* W1 = (const float*)d_in[9];
  const float* bf1 = (const float*)d_in[10];
  const float* W2 = (const float*)d_in[11];
  const float* bf2 = (const float*)d_in[12];
  float* outp = (float*)d_out;

  char* p = (char*)d_ws;
  u16* WqkvT = (u16*)p; p += (size_t)QKVN * DIMN * 2;
  u16* WprojT = (u16*)p; p += (size_t)DIMN * DIMN * 2;
  u16* W1T = (u16*)p; p += (size_t)HID * DIMN * 2;
  u16* W2T = (u16*)p; p += (size_t)DIMN * HID * 2;
  u16* bufX = (u16*)p; p += (size_t)BNROWS * DIMN * 2;  // h1 / attn_out / h2
  u16* big = (u16*)p; p += (size_t)BNROWS * HID * 2;    // qkv then ff1

  twb_k<<<dim3(QKVN / 32, DIMN / 32), 256, 0, stream>>>(Wqkv, WqkvT, DIMN, QKVN);
  twb_k<<<dim3(DIMN / 32, DIMN / 32), 256, 0, stream>>>(Wproj, WprojT, DIMN, DIMN);
  twb_k<<<dim3(HID / 32, DIMN / 32), 256, 0, stream>>>(W1, W1T, DIMN, HID);
  twb_k<<<dim3(DIMN / 32, HID / 32), 256, 0, stream>>>(W2, W2T, HID, DIMN);

  ln_k<<<BNROWS / 4, 256, 0, stream>>>(x, g1, b1, bufX);
  // QKV GEMM -> big (bf16), 256x256 tile
  gemm256_k<1, 0, 0><<<dim3(64, QKVN / 256), 512, 0, stream>>>(bufX, WqkvT, bqkv, nullptr,
                                                               big, QKVN, DIMN);
  // attention -> bufX (bf16)
  attn_k<<<1536, 256, 0, stream>>>(big, bufX);
  // proj GEMM + residual(x) -> d_out (fp32), 256x128 tile (N=768: 384 blocks, 2/CU)
  gemmP_k<0, 0, 1><<<dim3(64, DIMN / 128), 256, 0, stream>>>(bufX, WprojT, bproj, x, outp,
                                                             DIMN, DIMN);
  ln_k<<<BNROWS / 4, 256, 0, stream>>>(outp, g2, b2, bufX);
  // FF1 (relu) -> big (bf16), 256x256 tile
  gemm256_k<1, 1, 0><<<dim3(64, HID / 256), 512, 0, stream>>>(bufX, W1T, bf1, nullptr, big,
                                                              HID, DIMN);
  // FF2 + residual(d_out) -> d_out (fp32, in place), 256x128 tile
  gemmP_k<0, 0, 1><<<dim3(64, DIMN / 128), 256, 0, stream>>>(big, W2T, bf2, outp, outp,
                                                             DIMN, HID);
}

// Round 7
// 449.773 us; speedup vs baseline: 1.6705x; 1.0134x over previous
//
#include <hip/hip_runtime.h>
#include <cstdint>
#include <cstddef>

typedef unsigned short u16;
typedef __bf16 bf16x8 __attribute__((ext_vector_type(8)));
typedef unsigned short u16x8 __attribute__((ext_vector_type(8)));
typedef float f32x4 __attribute__((ext_vector_type(4)));

#define DIMN 768
#define BNROWS 16384
#define NH 12
#define HD 64
#define HID 3072
#define QKVN 2304

__device__ __forceinline__ u16 f2bf(float f) {
  unsigned u = __builtin_bit_cast(unsigned, f);
  u += 0x7fffu + ((u >> 16) & 1u);
  return (u16)(u >> 16);
}

__device__ __forceinline__ bf16x8 ld8(const u16* p) {
  u16x8 v = *reinterpret_cast<const u16x8*>(p);
  return __builtin_bit_cast(bf16x8, v);
}

__device__ __forceinline__ void gload16(const void* g, void* l) {
  __builtin_amdgcn_global_load_lds(
      (const __attribute__((address_space(1))) unsigned int*)g,
      (__attribute__((address_space(3))) unsigned int*)l, 16, 0, 0);
}

#define MFMA(a, b, c) __builtin_amdgcn_mfma_f32_16x16x32_bf16(a, b, c, 0, 0, 0)

// ---------------- weight transpose + cast: W[K,N] f32 -> Wt[N,K] bf16 ----------------
__global__ __launch_bounds__(256) void twb_k(const float* __restrict__ W,
                                             u16* __restrict__ Wt, int K, int N) {
  __shared__ float tile[32][33];
  const int n0 = blockIdx.x * 32, k0 = blockIdx.y * 32;
  const int tx = threadIdx.x & 31, ty = threadIdx.x >> 5;  // ty 0..7
#pragma unroll
  for (int i = 0; i < 4; i++)
    tile[ty + i * 8][tx] = W[(size_t)(k0 + ty + i * 8) * N + n0 + tx];
  __syncthreads();
#pragma unroll
  for (int i = 0; i < 4; i++)
    Wt[(size_t)(n0 + ty + i * 8) * K + k0 + tx] = f2bf(tile[tx][ty + i * 8]);
}

// ---------------- LayerNorm: fp32 row -> bf16 row (one wave per 768-row) ----------------
__global__ __launch_bounds__(256) void ln_k(const float* __restrict__ x,
                                            const float* __restrict__ g,
                                            const float* __restrict__ bta,
                                            u16* __restrict__ outp) {
  const int row = blockIdx.x * 4 + (threadIdx.x >> 6);
  const int lane = threadIdx.x & 63;
  const float4* xr = (const float4*)(x + (size_t)row * DIMN);
  float4 v[3];
  float s = 0.f, ss = 0.f;
#pragma unroll
  for (int c = 0; c < 3; c++) {
    v[c] = xr[c * 64 + lane];
    s += v[c].x + v[c].y + v[c].z + v[c].w;
    ss += v[c].x * v[c].x + v[c].y * v[c].y + v[c].z * v[c].z + v[c].w * v[c].w;
  }
#pragma unroll
  for (int off = 1; off < 64; off <<= 1) {
    s += __shfl_xor(s, off);
    ss += __shfl_xor(ss, off);
  }
  const float mu = s * (1.f / DIMN);
  const float var = ss * (1.f / DIMN) - mu * mu;
  const float rs = rsqrtf(var + 1e-5f);
  u16* orow = outp + (size_t)row * DIMN;
#pragma unroll
  for (int c = 0; c < 3; c++) {
    float4 gv = ((const float4*)g)[c * 64 + lane];
    float4 bv = ((const float4*)bta)[c * 64 + lane];
    ushort4 o;
    o.x = f2bf((v[c].x - mu) * rs * gv.x + bv.x);
    o.y = f2bf((v[c].y - mu) * rs * gv.y + bv.y);
    o.z = f2bf((v[c].z - mu) * rs * gv.z + bv.z);
    o.w = f2bf((v[c].w - mu) * rs * gv.w + bv.w);
    ((ushort4*)orow)[c * 64 + lane] = o;
  }
}

// ---------------- GEMM 256x256, 8 waves, BK=32, 4-slot LDS ring, counted vmcnt ----------
// T2 swizzle: LDS[row][u16-unit u] holds G-unit u^((row>>1)&3) (involution on 16B units).
// Staging pre-swizzles the GLOBAL source (LDS dest stays linear, rule #21); reads use
// rdoff = (lhi ^ ((llo>>1)&3))*16 since every read row = 16*m + llo. Quarter-wave b128
// reads now touch all 8 bank-slots (2 lanes/slot = free) instead of 2 (8-way conflict).
template <int OUT_BF16, int RELU, int RESID>
__global__ __launch_bounds__(512, 2) void gemm256_k(const u16* __restrict__ A,
                                                    const u16* __restrict__ Bt,
                                                    const float* __restrict__ bias,
                                                    const float* __restrict__ resid,
                                                    void* __restrict__ Cout, int N, int K) {
  __shared__ u16 lds[65536];  // 4 slots x (A 16KB + B 16KB) = 128 KiB
  const int tid = threadIdx.x;
  const int m0 = blockIdx.x * 256;
  const int n0 = blockIdx.y * 256;
  const int lane = tid & 63, w = tid >> 6;
  const int wr = w >> 2, wc = w & 3;  // 2 (M) x 4 (N) wave grid, per-wave C = 128x64
  const int lhi = lane >> 4, llo = lane & 15;
  const int rdoff = (lhi ^ ((llo >> 1) & 3)) * 16;  // swizzled 16B-unit byte offset
  const int NT = K >> 5;

  const int srow = tid >> 2;
  const int sc8 = ((tid & 3) ^ ((srow >> 1) & 3)) * 8;  // pre-swizzled source K-unit
  const u16* aS0 = A + (size_t)(m0 + srow) * K + sc8;
  const u16* aS1 = A + (size_t)(m0 + 128 + srow) * K + sc8;
  const u16* bS0 = Bt + (size_t)(n0 + srow) * K + sc8;
  const u16* bS1 = Bt + (size_t)(n0 + 128 + srow) * K + sc8;

  auto slotBase = [&](int t) -> char* { return (char*)lds + ((size_t)(t & 3) << 15); };
  auto stageA = [&](int t) {
    char* sb = slotBase(t);
    gload16(aS0 + t * 32, sb + tid * 16);
    gload16(aS1 + t * 32, sb + 8192 + tid * 16);
  };
  auto stageB = [&](int t) {
    char* sb = slotBase(t) + 16384;
    gload16(bS0 + t * 32, sb + tid * 16);
    gload16(bS1 + t * 32, sb + 8192 + tid * 16);
  };

  f32x4 acc[8][4] = {};

  stageA(0); stageB(0);
  stageA(1); stageB(1);
  stageA(2); stageB(2);
  asm volatile("s_waitcnt vmcnt(8)" ::: "memory");
  __builtin_amdgcn_s_barrier();

  for (int t = 0; t < NT; ++t) {
    const char* sb = slotBase(t);
    bf16x8 af[4], bfr[4];
#pragma unroll
    for (int ni = 0; ni < 4; ni++)
      bfr[ni] = ld8((const u16*)(sb + 16384 + (wc * 64 + ni * 16 + llo) * 64 + rdoff));
#pragma unroll
    for (int mi = 0; mi < 4; mi++)
      af[mi] = ld8((const u16*)(sb + (wr * 128 + mi * 16 + llo) * 64 + rdoff));
    if (t + 3 < NT) stageA(t + 3);
    __builtin_amdgcn_s_barrier();
    asm volatile("s_waitcnt lgkmcnt(0)" ::: "memory");
    __builtin_amdgcn_sched_barrier(0);
    __builtin_amdgcn_s_setprio(1);
#pragma unroll
    for (int mi = 0; mi < 4; mi++)
#pragma unroll
      for (int ni = 0; ni < 4; ni++) acc[mi][ni] = MFMA(af[mi], bfr[ni], acc[mi][ni]);
    __builtin_amdgcn_s_setprio(0);
    __builtin_amdgcn_sched_barrier(0);
    __builtin_amdgcn_s_barrier();
#pragma unroll
    for (int mi = 0; mi < 4; mi++)
      af[mi] = ld8((const u16*)(sb + (wr * 128 + 64 + mi * 16 + llo) * 64 + rdoff));
    if (t + 3 < NT) stageB(t + 3);
    __builtin_amdgcn_s_barrier();
    asm volatile("s_waitcnt lgkmcnt(0)" ::: "memory");
    __builtin_amdgcn_sched_barrier(0);
    __builtin_amdgcn_s_setprio(1);
#pragma unroll
    for (int mi = 0; mi < 4; mi++)
#pragma unroll
      for (int ni = 0; ni < 4; ni++) acc[4 + mi][ni] = MFMA(af[mi], bfr[ni], acc[4 + mi][ni]);
    __builtin_amdgcn_s_setprio(0);
    __builtin_amdgcn_sched_barrier(0);
    if (t + 3 < NT) {
      asm volatile("s_waitcnt vmcnt(8)" ::: "memory");
    } else if (t + 2 < NT) {
      asm volatile("s_waitcnt vmcnt(4)" ::: "memory");
    } else if (t + 1 < NT) {
      asm volatile("s_waitcnt vmcnt(0)" ::: "memory");
    }
    __builtin_amdgcn_s_barrier();
  }

#pragma unroll
  for (int mi = 0; mi < 8; mi++)
#pragma unroll
    for (int ni = 0; ni < 4; ni++) {
      const int row = m0 + wr * 128 + mi * 16 + lhi * 4;
      const int col = n0 + wc * 64 + ni * 16 + llo;
      const float bsv = bias[col];
#pragma unroll
      for (int rr = 0; rr < 4; rr++) {
        float v = acc[mi][ni][rr] + bsv;
        if (RELU) v = fmaxf(v, 0.0f);
        const size_t idx = (size_t)(row + rr) * N + col;
        if (RESID) v += resid[idx];
        if (OUT_BF16)
          ((u16*)Cout)[idx] = f2bf(v);
        else
          ((float*)Cout)[idx] = v;
      }
    }
}

// ---------------- GEMM 256x128, 4 waves, BK=32, 3-slot ring, 2 blocks/CU --------------
// Same T2 swizzle as gemm256 (source pre-swizzle + rdoff read).
template <int OUT_BF16, int RELU, int RESID>
__global__ __launch_bounds__(256, 2) void gemmP_k(const u16* __restrict__ A,
                                                  const u16* __restrict__ Bt,
                                                  const float* __restrict__ bias,
                                                  const float* __restrict__ resid,
                                                  void* __restrict__ Cout, int N, int K) {
  __shared__ u16 lds[3 * 12288];  // 3 slots x (A[256][32] 16KB + B[128][32] 8KB)
  const int tid = threadIdx.x;
  const int m0 = blockIdx.x * 256;
  const int n0 = blockIdx.y * 128;
  const int lane = tid & 63, w = tid >> 6;
  const int wr = w >> 1, wc = w & 1;  // 2 (M) x 2 (N) waves, per-wave C = 128x64
  const int lhi = lane >> 4, llo = lane & 15;
  const int rdoff = (lhi ^ ((llo >> 1) & 3)) * 16;
  const int NT = K >> 5;

  const int crow = tid >> 2;
  const int kc8 = ((tid & 3) ^ ((crow >> 1) & 3)) * 8;  // pre-swizzled source K-unit
  const u16* aS = A + (size_t)(m0 + crow) * K + kc8;   // + 64*s rows
  const u16* bS = Bt + (size_t)(n0 + crow) * K + kc8;  // + 64*s rows (s<2)
  const size_t a64 = (size_t)64 * K;

  auto slotBase = [&](int t) -> char* { return (char*)lds + (t % 3) * 24576; };
  auto stage1 = [&](int t) {  // A rows 0..127, B rows 0..63
    char* sb = slotBase(t);
    gload16(aS + t * 32, sb + tid * 16);
    gload16(aS + a64 + t * 32, sb + 4096 + tid * 16);
    gload16(bS + t * 32, sb + 16384 + tid * 16);
  };
  auto stage2 = [&](int t) {  // A rows 128..255, B rows 64..127
    char* sb = slotBase(t);
    gload16(aS + 2 * a64 + t * 32, sb + 8192 + tid * 16);
    gload16(aS + 3 * a64 + t * 32, sb + 12288 + tid * 16);
    gload16(bS + a64 + t * 32, sb + 16384 + 4096 + tid * 16);
  };

  f32x4 acc[8][4] = {};

  stage1(0); stage2(0);
  stage1(1); stage2(1);
  asm volatile("s_waitcnt vmcnt(6)" ::: "memory");
  __builtin_amdgcn_s_barrier();

  for (int t = 0; t < NT; ++t) {
    const char* sb = slotBase(t);
    bf16x8 af[4], bfr[4];
#pragma unroll
    for (int ni = 0; ni < 4; ni++)
      bfr[ni] = ld8((const u16*)(sb + 16384 + (wc * 64 + ni * 16 + llo) * 64 + rdoff));
#pragma unroll
    for (int mi = 0; mi < 4; mi++)
      af[mi] = ld8((const u16*)(sb + (wr * 128 + mi * 16 + llo) * 64 + rdoff));
    if (t + 2 < NT) stage1(t + 2);
    __builtin_amdgcn_s_barrier();
    asm volatile("s_waitcnt lgkmcnt(0)" ::: "memory");
    __builtin_amdgcn_sched_barrier(0);
    __builtin_amdgcn_s_setprio(1);
#pragma unroll
    for (int mi = 0; mi < 4; mi++)
#pragma unroll
      for (int ni = 0; ni < 4; ni++) acc[mi][ni] = MFMA(af[mi], bfr[ni], acc[mi][ni]);
    __builtin_amdgcn_s_setprio(0);
    __builtin_amdgcn_sched_barrier(0);
    __builtin_amdgcn_s_barrier();
#pragma unroll
    for (int mi = 0; mi < 4; mi++)
      af[mi] = ld8((const u16*)(sb + (wr * 128 + 64 + mi * 16 + llo) * 64 + rdoff));
    if (t + 2 < NT) stage2(t + 2);
    __builtin_amdgcn_s_barrier();
    asm volatile("s_waitcnt lgkmcnt(0)" ::: "memory");
    __builtin_amdgcn_sched_barrier(0);
    __builtin_amdgcn_s_setprio(1);
#pragma unroll
    for (int mi = 0; mi < 4; mi++)
#pragma unroll
      for (int ni = 0; ni < 4; ni++) acc[4 + mi][ni] = MFMA(af[mi], bfr[ni], acc[4 + mi][ni]);
    __builtin_amdgcn_s_setprio(0);
    __builtin_amdgcn_sched_barrier(0);
    if (t + 2 < NT) {
      asm volatile("s_waitcnt vmcnt(6)" ::: "memory");
    } else if (t + 1 < NT) {
      asm volatile("s_waitcnt vmcnt(0)" ::: "memory");
    }
    __builtin_amdgcn_s_barrier();
  }

#pragma unroll
  for (int mi = 0; mi < 8; mi++)
#pragma unroll
    for (int ni = 0; ni < 4; ni++) {
      const int row = m0 + wr * 128 + mi * 16 + lhi * 4;
      const int col = n0 + wc * 64 + ni * 16 + llo;
      const float bsv = bias[col];
#pragma unroll
      for (int rr = 0; rr < 4; rr++) {
        float v = acc[mi][ni][rr] + bsv;
        if (RELU) v = fmaxf(v, 0.0f);
        const size_t idx = (size_t)(row + rr) * N + col;
        if (RESID) v += resid[idx];
        if (OUT_BF16)
          ((u16*)Cout)[idx] = f2bf(v);
        else
          ((float*)Cout)[idx] = v;
      }
    }
}

// ---------------- fused attention (pipelined) ----------------
__device__ __forceinline__ bf16x8 ldscale8(const u16* p, float c) {
  u16x8 v = *reinterpret_cast<const u16x8*>(p);
  bf16x8 r;
#pragma unroll
  for (int j = 0; j < 8; j++) {
    float f = __builtin_bit_cast(float, (unsigned)v[j] << 16) * c;
    r[j] = (__bf16)f;
  }
  return r;
}

__device__ __forceinline__ unsigned pack_bf2(float a, float b) {
  unsigned ua = (unsigned)__builtin_bit_cast(u16, (__bf16)a);
  unsigned ub = (unsigned)__builtin_bit_cast(u16, (__bf16)b);
  return ua | (ub << 16);
}

__global__ __launch_bounds__(256) void attn_k(const u16* __restrict__ qkv,
                                              u16* __restrict__ outp) {
  __shared__ u16 Ks[2][64 * 64];  // K[kv][d], 16B-unit u swizzled: holds G-unit u^(kv&7)
  __shared__ u16 Vt[2][64 * 64];  // V^T[d][kv], kv swizzled by ((d&7)*8)
  __shared__ u16 Ps[4][32 * 64];  // per-wave P[q][kv], kv swizzled by ((q&7)*8)

  const int tid = threadIdx.x;
  const int f = blockIdx.x;                  // 0..1535
  const int bh = (f & 7) | ((f >> 6) << 3);  // all 8 q-tiles of one bh on one XCD
  const int qt = (f >> 3) & 7;
  const int b = bh / NH, h = bh - b * NH;
  const int lane = tid & 63, w = tid >> 6;
  const int lhi = lane >> 4, llo = lane & 15;
  const size_t rowb = (size_t)b * 1024;
  const int wq0 = qt * 128 + w * 32;
  const float SC = 0.052059750f;  // 768^-0.5 * log2(e)

  bf16x8 qb[2][2];
#pragma unroll
  for (int mi = 0; mi < 2; mi++) {
    const u16* qrow = qkv + (rowb + wq0 + mi * 16 + llo) * QKVN + h * HD;
    qb[mi][0] = ldscale8(qrow + lhi * 8, SC);
    qb[mi][1] = ldscale8(qrow + 32 + lhi * 8, SC);
  }

  const u16* kbase = qkv + rowb * QKVN + DIMN + h * HD;
  const u16* vbase = qkv + rowb * QKVN + 2 * DIMN + h * HD;
  const int vc8 = w * 8;
  const int sw = (llo & 7) * 8;
  const int rsw = llo & 7;

  const int srow = tid >> 3, su = tid & 7;
  const u16* ksrc = kbase + (size_t)srow * QKVN + (su ^ (srow & 7)) * 8;

  auto stageK = [&](int kt, int buf) {
    const u16* s0 = ksrc + (size_t)kt * 64 * QKVN;
    gload16(s0, (char*)&Ks[buf][0] + tid * 16);
    gload16(s0 + (size_t)32 * QKVN, (char*)&Ks[buf][0] + 4096 + tid * 16);
  };
  auto loadV = [&](int kt, u16x8& a, u16x8& c) {
    const u16* vr = vbase + (size_t)(kt * 64 + lane) * QKVN + vc8;
    a = *reinterpret_cast<const u16x8*>(vr);
    c = *reinterpret_cast<const u16x8*>(vr + 32);
  };
  auto writeV = [&](int buf, u16x8 a, u16x8 c) {
#pragma unroll
    for (int j = 0; j < 8; j++) {
      Vt[buf][(vc8 + j) * 64 + (lane ^ (j * 8))] = a[j];
      Vt[buf][(vc8 + 32 + j) * 64 + (lane ^ (j * 8))] = c[j];
    }
  };

  u16x8 v0, v1, nv0, nv1;

  stageK(0, 0);
  loadV(0, v0, v1);
  stageK(1, 1);
  asm volatile("s_waitcnt vmcnt(2)" ::: "memory");
  writeV(0, v0, v1);
  asm volatile("s_waitcnt lgkmcnt(0)" ::: "memory");
  __builtin_amdgcn_s_barrier();
  __builtin_amdgcn_sched_barrier(0);

  float psum[2] = {0.f, 0.f};
  f32x4 oacc[2][4] = {};

  for (int t = 0; t < 16; t++) {
    if (t < 15) loadV(t + 1, nv0, nv1);

    const u16* kB = &Ks[t & 1][0];
    f32x4 sacc[4][2] = {};
#pragma unroll
    for (int ks = 0; ks < 2; ks++)
#pragma unroll
      for (int ni = 0; ni < 4; ni++) {
        bf16x8 kf = ld8(&kB[(ni * 16 + llo) * 64 + (((ks * 4 + lhi) ^ rsw) * 8)]);
#pragma unroll
        for (int mi = 0; mi < 2; mi++) sacc[ni][mi] = MFMA(kf, qb[mi][ks], sacc[ni][mi]);
      }

    asm volatile("s_waitcnt lgkmcnt(0)" ::: "memory");
    __builtin_amdgcn_s_barrier();  // all waves done reading Ks[t&1]
    __builtin_amdgcn_sched_barrier(0);
    if (t + 2 < 16) stageK(t + 2, t & 1);

#pragma unroll
    for (int mi = 0; mi < 2; mi++)
#pragma unroll
      for (int ni = 0; ni < 4; ni++) {
        float p0 = __builtin_amdgcn_exp2f(sacc[ni][mi][0]);
        float p1 = __builtin_amdgcn_exp2f(sacc[ni][mi][1]);
        float p2 = __builtin_amdgcn_exp2f(sacc[ni][mi][2]);
        float p3 = __builtin_amdgcn_exp2f(sacc[ni][mi][3]);
        psum[mi] += (p0 + p1) + (p2 + p3);
        u16* pp = &Ps[w][(mi * 16 + llo) * 64 + ((ni * 16 + lhi * 4) ^ sw)];
        uint2 pw;
        pw.x = pack_bf2(p0, p1);
        pw.y = pack_bf2(p2, p3);
        *reinterpret_cast<uint2*>(pp) = pw;  // ds_write_b64
      }

#pragma unroll
    for (int ks = 0; ks < 2; ks++) {
      const int koff = ks * 32 + lhi * 8;
      bf16x8 pa0 = ld8(&Ps[w][llo * 64 + (koff ^ sw)]);
      bf16x8 pa1 = ld8(&Ps[w][(16 + llo) * 64 + (koff ^ sw)]);
#pragma unroll
      for (int ni = 0; ni < 4; ni++) {
        bf16x8 vb = ld8(&Vt[t & 1][(ni * 16 + llo) * 64 + (koff ^ sw)]);
        oacc[0][ni] = MFMA(pa0, vb, oacc[0][ni]);
        oacc[1][ni] = MFMA(pa1, vb, oacc[1][ni]);
      }
    }

    if (t < 15) {
      if (t + 2 < 16) {
        asm volatile("s_waitcnt vmcnt(2)" ::: "memory");
      } else {
        asm volatile("s_waitcnt vmcnt(0)" ::: "memory");
      }
      writeV((t + 1) & 1, nv0, nv1);
      v0 = nv0; v1 = nv1;
      asm volatile("s_waitcnt lgkmcnt(0)" ::: "memory");
      __builtin_amdgcn_s_barrier();
      __builtin_amdgcn_sched_barrier(0);
    }
  }

  float rl[2][4];
#pragma unroll
  for (int mi = 0; mi < 2; mi++) {
    psum[mi] += __shfl_xor(psum[mi], 16);
    psum[mi] += __shfl_xor(psum[mi], 32);
#pragma unroll
    for (int r = 0; r < 4; r++) rl[mi][r] = 1.0f / __shfl(psum[mi], lhi * 4 + r);
  }

#pragma unroll
  for (int mi = 0; mi < 2; mi++)
#pragma unroll
    for (int ni = 0; ni < 4; ni++)
#pragma unroll
      for (int r = 0; r < 4; r++) {
        const size_t row = rowb + wq0 + mi * 16 + lhi * 4 + r;
        outp[row * DIMN + h * HD + ni * 16 + llo] = f2bf(oacc[mi][ni][r] * rl[mi][r]);
      }
}

extern "C" void kernel_launch(void* const* d_in, const int* in_sizes, int n_in,
                              void* d_out, int out_size, void* d_ws, size_t ws_size,
                              hipStream_t stream) {
  const float* x = (const float*)d_in[0];
  const float* Wqkv = (const float*)d_in[1];
  const float* bqkv = (const float*)d_in[2];
  const float* Wproj = (const float*)d_in[3];
  const float* bproj = (const float*)d_in[4];
  const float* g1 = (const float*)d_in[5];
  const float* b1 = (const float*)d_in[6];
  const float* g2 = (const float*)d_in[7];
  const float* b2 = (const float*)d_in[8];
  const float* W1 = (const float*)d_in[9];
  const float* bf1 = (const float*)d_in[10];
  const float* W2 = (const float*)d_in[11];
  const float* bf2 = (const float*)d_in[12];
  float* outp = (float*)d_out;

  char* p = (char*)d_ws;
  u16* WqkvT = (u16*)p; p += (size_t)QKVN * DIMN * 2;
  u16* WprojT = (u16*)p; p += (size_t)DIMN * DIMN * 2;
  u16* W1T = (u16*)p; p += (size_t)HID * DIMN * 2;
  u16* W2T = (u16*)p; p += (size_t)DIMN * HID * 2;
  u16* bufX = (u16*)p; p += (size_t)BNROWS * DIMN * 2;  // h1 / attn_out / h2
  u16* big = (u16*)p; p += (size_t)BNROWS * HID * 2;    // qkv then ff1

  twb_k<<<dim3(QKVN / 32, DIMN / 32), 256, 0, stream>>>(Wqkv, WqkvT, DIMN, QKVN);
  twb_k<<<dim3(DIMN / 32, DIMN / 32), 256, 0, stream>>>(Wproj, WprojT, DIMN, DIMN);
  twb_k<<<dim3(HID / 32, DIMN / 32), 256, 0, stream>>>(W1, W1T, DIMN, HID);
  twb_k<<<dim3(DIMN / 32, HID / 32), 256, 0, stream>>>(W2, W2T, HID, DIMN);

  ln_k<<<BNROWS / 4, 256, 0, stream>>>(x, g1, b1, bufX);
  // QKV GEMM -> big (bf16), 256x256 tile
  gemm256_k<1, 0, 0><<<dim3(64, QKVN / 256), 512, 0, stream>>>(bufX, WqkvT, bqkv, nullptr,
                                                               big, QKVN, DIMN);
  // attention -> bufX (bf16)
  attn_k<<<1536, 256, 0, stream>>>(big, bufX);
  // proj GEMM + residual(x) -> d_out (fp32), 256x128 tile (N=768: 384 blocks, 2/CU)
  gemmP_k<0, 0, 1><<<dim3(64, DIMN / 128), 256, 0, stream>>>(bufX, WprojT, bproj, x, outp,
                                                             DIMN, DIMN);
  ln_k<<<BNROWS / 4, 256, 0, stream>>>(outp, g2, b2, bufX);
  // FF1 (relu) -> big (bf16), 256x256 tile
  gemm256_k<1, 1, 0><<<dim3(64, HID / 256), 512, 0, stream>>>(bufX, W1T, bf1, nullptr, big,
                                                              HID, DIMN);
  // FF2 + residual(d_out) -> d_out (fp32, in place), 256x128 tile
  gemmP_k<0, 0, 1><<<dim3(64, DIMN / 128), 256, 0, stream>>>(big, W2T, bf2, outp, outp,
                                                             DIMN, HID);
}

// Round 8
// 442.809 us; speedup vs baseline: 1.6968x; 1.0157x over previous
//
#include <hip/hip_runtime.h>
#include <cstdint>
#include <cstddef>

typedef unsigned short u16;
typedef __bf16 bf16x8 __attribute__((ext_vector_type(8)));
typedef unsigned short u16x8 __attribute__((ext_vector_type(8)));
typedef float f32x4 __attribute__((ext_vector_type(4)));

#define DIMN 768
#define BNROWS 16384
#define NH 12
#define HD 64
#define HID 3072
#define QKVN 2304

__device__ __forceinline__ u16 f2bf(float f) {
  unsigned u = __builtin_bit_cast(unsigned, f);
  u += 0x7fffu + ((u >> 16) & 1u);
  return (u16)(u >> 16);
}

__device__ __forceinline__ bf16x8 ld8(const u16* p) {
  u16x8 v = *reinterpret_cast<const u16x8*>(p);
  return __builtin_bit_cast(bf16x8, v);
}

__device__ __forceinline__ void gload16(const void* g, void* l) {
  __builtin_amdgcn_global_load_lds(
      (const __attribute__((address_space(1))) unsigned int*)g,
      (__attribute__((address_space(3))) unsigned int*)l, 16, 0, 0);
}

#define MFMA(a, b, c) __builtin_amdgcn_mfma_f32_16x16x32_bf16(a, b, c, 0, 0, 0)

// ---------------- weight transpose + cast: W[K,N] f32 -> Wt[N,K] bf16 ----------------
__global__ __launch_bounds__(256) void twb_k(const float* __restrict__ W,
                                             u16* __restrict__ Wt, int K, int N) {
  __shared__ float tile[32][33];
  const int n0 = blockIdx.x * 32, k0 = blockIdx.y * 32;
  const int tx = threadIdx.x & 31, ty = threadIdx.x >> 5;  // ty 0..7
#pragma unroll
  for (int i = 0; i < 4; i++)
    tile[ty + i * 8][tx] = W[(size_t)(k0 + ty + i * 8) * N + n0 + tx];
  __syncthreads();
#pragma unroll
  for (int i = 0; i < 4; i++)
    Wt[(size_t)(n0 + ty + i * 8) * K + k0 + tx] = f2bf(tile[tx][ty + i * 8]);
}

// ---------------- LayerNorm: fp32 row -> bf16 row (one wave per 768-row) ----------------
__global__ __launch_bounds__(256) void ln_k(const float* __restrict__ x,
                                            const float* __restrict__ g,
                                            const float* __restrict__ bta,
                                            u16* __restrict__ outp) {
  const int row = blockIdx.x * 4 + (threadIdx.x >> 6);
  const int lane = threadIdx.x & 63;
  const float4* xr = (const float4*)(x + (size_t)row * DIMN);
  float4 v[3];
  float s = 0.f, ss = 0.f;
#pragma unroll
  for (int c = 0; c < 3; c++) {
    v[c] = xr[c * 64 + lane];
    s += v[c].x + v[c].y + v[c].z + v[c].w;
    ss += v[c].x * v[c].x + v[c].y * v[c].y + v[c].z * v[c].z + v[c].w * v[c].w;
  }
#pragma unroll
  for (int off = 1; off < 64; off <<= 1) {
    s += __shfl_xor(s, off);
    ss += __shfl_xor(ss, off);
  }
  const float mu = s * (1.f / DIMN);
  const float var = ss * (1.f / DIMN) - mu * mu;
  const float rs = rsqrtf(var + 1e-5f);
  u16* orow = outp + (size_t)row * DIMN;
#pragma unroll
  for (int c = 0; c < 3; c++) {
    float4 gv = ((const float4*)g)[c * 64 + lane];
    float4 bv = ((const float4*)bta)[c * 64 + lane];
    ushort4 o;
    o.x = f2bf((v[c].x - mu) * rs * gv.x + bv.x);
    o.y = f2bf((v[c].y - mu) * rs * gv.y + bv.y);
    o.z = f2bf((v[c].z - mu) * rs * gv.z + bv.z);
    o.w = f2bf((v[c].w - mu) * rs * gv.w + bv.w);
    ((ushort4*)orow)[c * 64 + lane] = o;
  }
}

// ---------------- GEMM 256x256, 8 waves, BK=32, 4-slot ring, ONE barrier/tile ----------
// Merged-phase schedule. Sync ledger:
//  - slot WAR: stage(t+3) writes slot (t-1)&3; all waves passed tile t-1's closing
//    barrier (having drained lgkmcnt(0) before their MFMA) before any wave enters
//    tile t and issues the stage -> reads of that slot are complete.
//  - RAW: boundary vmcnt(8) at end of tile t-1 guarantees tile t's 4 loads landed.
//  - counted vmcnt never drains to 0 in steady state (T4).
// T2 swizzle: LDS holds G-unit u^((row>>1)&3); reads use rdoff (see R6).
template <int OUT_BF16, int RELU, int RESID>
__global__ __launch_bounds__(512, 2) void gemm256_k(const u16* __restrict__ A,
                                                    const u16* __restrict__ Bt,
                                                    const float* __restrict__ bias,
                                                    const float* __restrict__ resid,
                                                    void* __restrict__ Cout, int N, int K) {
  __shared__ u16 lds[65536];  // 4 slots x (A 16KB + B 16KB) = 128 KiB
  const int tid = threadIdx.x;
  const int m0 = blockIdx.x * 256;
  const int n0 = blockIdx.y * 256;
  const int lane = tid & 63, w = tid >> 6;
  const int wr = w >> 2, wc = w & 3;  // 2 (M) x 4 (N) wave grid, per-wave C = 128x64
  const int lhi = lane >> 4, llo = lane & 15;
  const int rdoff = (lhi ^ ((llo >> 1) & 3)) * 16;  // swizzled 16B-unit byte offset
  const int NT = K >> 5;

  const int srow = tid >> 2;
  const int sc8 = ((tid & 3) ^ ((srow >> 1) & 3)) * 8;  // pre-swizzled source K-unit
  const u16* aS0 = A + (size_t)(m0 + srow) * K + sc8;
  const u16* aS1 = A + (size_t)(m0 + 128 + srow) * K + sc8;
  const u16* bS0 = Bt + (size_t)(n0 + srow) * K + sc8;
  const u16* bS1 = Bt + (size_t)(n0 + 128 + srow) * K + sc8;

  auto slotBase = [&](int t) -> char* { return (char*)lds + ((size_t)(t & 3) << 15); };
  auto stageAB = [&](int t) {
    char* sb = slotBase(t);
    gload16(aS0 + t * 32, sb + tid * 16);
    gload16(aS1 + t * 32, sb + 8192 + tid * 16);
    gload16(bS0 + t * 32, sb + 16384 + tid * 16);
    gload16(bS1 + t * 32, sb + 16384 + 8192 + tid * 16);
  };

  f32x4 acc[8][4] = {};

  stageAB(0);
  stageAB(1);
  stageAB(2);
  asm volatile("s_waitcnt vmcnt(8)" ::: "memory");
  __builtin_amdgcn_s_barrier();

  for (int t = 0; t < NT; ++t) {
    const char* sb = slotBase(t);
    bf16x8 af[8], bfr[4];
#pragma unroll
    for (int ni = 0; ni < 4; ni++)
      bfr[ni] = ld8((const u16*)(sb + 16384 + (wc * 64 + ni * 16 + llo) * 64 + rdoff));
#pragma unroll
    for (int mi = 0; mi < 8; mi++)
      af[mi] = ld8((const u16*)(sb + (wr * 128 + mi * 16 + llo) * 64 + rdoff));
    if (t + 3 < NT) stageAB(t + 3);
    asm volatile("s_waitcnt lgkmcnt(0)" ::: "memory");
    __builtin_amdgcn_sched_barrier(0);
    __builtin_amdgcn_s_setprio(1);
#pragma unroll
    for (int mi = 0; mi < 8; mi++)
#pragma unroll
      for (int ni = 0; ni < 4; ni++) acc[mi][ni] = MFMA(af[mi], bfr[ni], acc[mi][ni]);
    __builtin_amdgcn_s_setprio(0);
    __builtin_amdgcn_sched_barrier(0);
    if (t + 3 < NT) {
      asm volatile("s_waitcnt vmcnt(8)" ::: "memory");
    } else if (t + 2 < NT) {
      asm volatile("s_waitcnt vmcnt(4)" ::: "memory");
    } else if (t + 1 < NT) {
      asm volatile("s_waitcnt vmcnt(0)" ::: "memory");
    }
    __builtin_amdgcn_s_barrier();
  }

#pragma unroll
  for (int mi = 0; mi < 8; mi++)
#pragma unroll
    for (int ni = 0; ni < 4; ni++) {
      const int row = m0 + wr * 128 + mi * 16 + lhi * 4;
      const int col = n0 + wc * 64 + ni * 16 + llo;
      const float bsv = bias[col];
#pragma unroll
      for (int rr = 0; rr < 4; rr++) {
        float v = acc[mi][ni][rr] + bsv;
        if (RELU) v = fmaxf(v, 0.0f);
        const size_t idx = (size_t)(row + rr) * N + col;
        if (RESID) v += resid[idx];
        if (OUT_BF16)
          ((u16*)Cout)[idx] = f2bf(v);
        else
          ((float*)Cout)[idx] = v;
      }
    }
}

// ---------------- GEMM 256x128, 4 waves, BK=32, 3-slot ring, ONE barrier/tile ---------
// Same merged-phase schedule as gemm256 (6 gloads/tile, 2-deep -> boundary vmcnt(6)).
template <int OUT_BF16, int RELU, int RESID>
__global__ __launch_bounds__(256, 2) void gemmP_k(const u16* __restrict__ A,
                                                  const u16* __restrict__ Bt,
                                                  const float* __restrict__ bias,
                                                  const float* __restrict__ resid,
                                                  void* __restrict__ Cout, int N, int K) {
  __shared__ u16 lds[3 * 12288];  // 3 slots x (A[256][32] 16KB + B[128][32] 8KB)
  const int tid = threadIdx.x;
  const int m0 = blockIdx.x * 256;
  const int n0 = blockIdx.y * 128;
  const int lane = tid & 63, w = tid >> 6;
  const int wr = w >> 1, wc = w & 1;  // 2 (M) x 2 (N) waves, per-wave C = 128x64
  const int lhi = lane >> 4, llo = lane & 15;
  const int rdoff = (lhi ^ ((llo >> 1) & 3)) * 16;
  const int NT = K >> 5;

  const int crow = tid >> 2;
  const int kc8 = ((tid & 3) ^ ((crow >> 1) & 3)) * 8;  // pre-swizzled source K-unit
  const u16* aS = A + (size_t)(m0 + crow) * K + kc8;   // + 64*s rows
  const u16* bS = Bt + (size_t)(n0 + crow) * K + kc8;  // + 64*s rows (s<2)
  const size_t a64 = (size_t)64 * K;

  auto slotBase = [&](int t) -> char* { return (char*)lds + (t % 3) * 24576; };
  auto stageAll = [&](int t) {
    char* sb = slotBase(t);
    gload16(aS + t * 32, sb + tid * 16);
    gload16(aS + a64 + t * 32, sb + 4096 + tid * 16);
    gload16(aS + 2 * a64 + t * 32, sb + 8192 + tid * 16);
    gload16(aS + 3 * a64 + t * 32, sb + 12288 + tid * 16);
    gload16(bS + t * 32, sb + 16384 + tid * 16);
    gload16(bS + a64 + t * 32, sb + 16384 + 4096 + tid * 16);
  };

  f32x4 acc[8][4] = {};

  stageAll(0);
  stageAll(1);
  asm volatile("s_waitcnt vmcnt(6)" ::: "memory");
  __builtin_amdgcn_s_barrier();

  for (int t = 0; t < NT; ++t) {
    const char* sb = slotBase(t);
    bf16x8 af[8], bfr[4];
#pragma unroll
    for (int ni = 0; ni < 4; ni++)
      bfr[ni] = ld8((const u16*)(sb + 16384 + (wc * 64 + ni * 16 + llo) * 64 + rdoff));
#pragma unroll
    for (int mi = 0; mi < 8; mi++)
      af[mi] = ld8((const u16*)(sb + (wr * 128 + mi * 16 + llo) * 64 + rdoff));
    if (t + 2 < NT) stageAll(t + 2);
    asm volatile("s_waitcnt lgkmcnt(0)" ::: "memory");
    __builtin_amdgcn_sched_barrier(0);
    __builtin_amdgcn_s_setprio(1);
#pragma unroll
    for (int mi = 0; mi < 8; mi++)
#pragma unroll
      for (int ni = 0; ni < 4; ni++) acc[mi][ni] = MFMA(af[mi], bfr[ni], acc[mi][ni]);
    __builtin_amdgcn_s_setprio(0);
    __builtin_amdgcn_sched_barrier(0);
    if (t + 2 < NT) {
      asm volatile("s_waitcnt vmcnt(6)" ::: "memory");
    } else if (t + 1 < NT) {
      asm volatile("s_waitcnt vmcnt(0)" ::: "memory");
    }
    __builtin_amdgcn_s_barrier();
  }

#pragma unroll
  for (int mi = 0; mi < 8; mi++)
#pragma unroll
    for (int ni = 0; ni < 4; ni++) {
      const int row = m0 + wr * 128 + mi * 16 + lhi * 4;
      const int col = n0 + wc * 64 + ni * 16 + llo;
      const float bsv = bias[col];
#pragma unroll
      for (int rr = 0; rr < 4; rr++) {
        float v = acc[mi][ni][rr] + bsv;
        if (RELU) v = fmaxf(v, 0.0f);
        const size_t idx = (size_t)(row + rr) * N + col;
        if (RESID) v += resid[idx];
        if (OUT_BF16)
          ((u16*)Cout)[idx] = f2bf(v);
        else
          ((float*)Cout)[idx] = v;
      }
    }
}

// ---------------- fused attention (pipelined) ----------------
__device__ __forceinline__ bf16x8 ldscale8(const u16* p, float c) {
  u16x8 v = *reinterpret_cast<const u16x8*>(p);
  bf16x8 r;
#pragma unroll
  for (int j = 0; j < 8; j++) {
    float f = __builtin_bit_cast(float, (unsigned)v[j] << 16) * c;
    r[j] = (__bf16)f;
  }
  return r;
}

__device__ __forceinline__ unsigned pack_bf2(float a, float b) {
  unsigned ua = (unsigned)__builtin_bit_cast(u16, (__bf16)a);
  unsigned ub = (unsigned)__builtin_bit_cast(u16, (__bf16)b);
  return ua | (ub << 16);
}

__global__ __launch_bounds__(256) void attn_k(const u16* __restrict__ qkv,
                                              u16* __restrict__ outp) {
  __shared__ u16 Ks[2][64 * 64];  // K[kv][d], 16B-unit u swizzled: holds G-unit u^(kv&7)
  __shared__ u16 Vt[2][64 * 64];  // V^T[d][kv], kv swizzled by ((d&7)*8)
  __shared__ u16 Ps[4][32 * 64];  // per-wave P[q][kv], kv swizzled by ((q&7)*8)

  const int tid = threadIdx.x;
  const int f = blockIdx.x;                  // 0..1535
  const int bh = (f & 7) | ((f >> 6) << 3);  // all 8 q-tiles of one bh on one XCD
  const int qt = (f >> 3) & 7;
  const int b = bh / NH, h = bh - b * NH;
  const int lane = tid & 63, w = tid >> 6;
  const int lhi = lane >> 4, llo = lane & 15;
  const size_t rowb = (size_t)b * 1024;
  const int wq0 = qt * 128 + w * 32;
  const float SC = 0.052059750f;  // 768^-0.5 * log2(e)

  bf16x8 qb[2][2];
#pragma unroll
  for (int mi = 0; mi < 2; mi++) {
    const u16* qrow = qkv + (rowb + wq0 + mi * 16 + llo) * QKVN + h * HD;
    qb[mi][0] = ldscale8(qrow + lhi * 8, SC);
    qb[mi][1] = ldscale8(qrow + 32 + lhi * 8, SC);
  }

  const u16* kbase = qkv + rowb * QKVN + DIMN + h * HD;
  const u16* vbase = qkv + rowb * QKVN + 2 * DIMN + h * HD;
  const int vc8 = w * 8;
  const int sw = (llo & 7) * 8;
  const int rsw = llo & 7;

  const int srow = tid >> 3, su = tid & 7;
  const u16* ksrc = kbase + (size_t)srow * QKVN + (su ^ (srow & 7)) * 8;

  auto stageK = [&](int kt, int buf) {
    const u16* s0 = ksrc + (size_t)kt * 64 * QKVN;
    gload16(s0, (char*)&Ks[buf][0] + tid * 16);
    gload16(s0 + (size_t)32 * QKVN, (char*)&Ks[buf][0] + 4096 + tid * 16);
  };
  auto loadV = [&](int kt, u16x8& a, u16x8& c) {
    const u16* vr = vbase + (size_t)(kt * 64 + lane) * QKVN + vc8;
    a = *reinterpret_cast<const u16x8*>(vr);
    c = *reinterpret_cast<const u16x8*>(vr + 32);
  };
  auto writeV = [&](int buf, u16x8 a, u16x8 c) {
#pragma unroll
    for (int j = 0; j < 8; j++) {
      Vt[buf][(vc8 + j) * 64 + (lane ^ (j * 8))] = a[j];
      Vt[buf][(vc8 + 32 + j) * 64 + (lane ^ (j * 8))] = c[j];
    }
  };

  u16x8 v0, v1, nv0, nv1;

  stageK(0, 0);
  loadV(0, v0, v1);
  stageK(1, 1);
  asm volatile("s_waitcnt vmcnt(2)" ::: "memory");
  writeV(0, v0, v1);
  asm volatile("s_waitcnt lgkmcnt(0)" ::: "memory");
  __builtin_amdgcn_s_barrier();
  __builtin_amdgcn_sched_barrier(0);

  float psum[2] = {0.f, 0.f};
  f32x4 oacc[2][4] = {};

  for (int t = 0; t < 16; t++) {
    if (t < 15) loadV(t + 1, nv0, nv1);

    const u16* kB = &Ks[t & 1][0];
    f32x4 sacc[4][2] = {};
#pragma unroll
    for (int ks = 0; ks < 2; ks++)
#pragma unroll
      for (int ni = 0; ni < 4; ni++) {
        bf16x8 kf = ld8(&kB[(ni * 16 + llo) * 64 + (((ks * 4 + lhi) ^ rsw) * 8)]);
#pragma unroll
        for (int mi = 0; mi < 2; mi++) sacc[ni][mi] = MFMA(kf, qb[mi][ks], sacc[ni][mi]);
      }

    asm volatile("s_waitcnt lgkmcnt(0)" ::: "memory");
    __builtin_amdgcn_s_barrier();  // all waves done reading Ks[t&1]
    __builtin_amdgcn_sched_barrier(0);
    if (t + 2 < 16) stageK(t + 2, t & 1);

#pragma unroll
    for (int mi = 0; mi < 2; mi++)
#pragma unroll
      for (int ni = 0; ni < 4; ni++) {
        float p0 = __builtin_amdgcn_exp2f(sacc[ni][mi][0]);
        float p1 = __builtin_amdgcn_exp2f(sacc[ni][mi][1]);
        float p2 = __builtin_amdgcn_exp2f(sacc[ni][mi][2]);
        float p3 = __builtin_amdgcn_exp2f(sacc[ni][mi][3]);
        psum[mi] += (p0 + p1) + (p2 + p3);
        u16* pp = &Ps[w][(mi * 16 + llo) * 64 + ((ni * 16 + lhi * 4) ^ sw)];
        uint2 pw;
        pw.x = pack_bf2(p0, p1);
        pw.y = pack_bf2(p2, p3);
        *reinterpret_cast<uint2*>(pp) = pw;  // ds_write_b64
      }

#pragma unroll
    for (int ks = 0; ks < 2; ks++) {
      const int koff = ks * 32 + lhi * 8;
      bf16x8 pa0 = ld8(&Ps[w][llo * 64 + (koff ^ sw)]);
      bf16x8 pa1 = ld8(&Ps[w][(16 + llo) * 64 + (koff ^ sw)]);
#pragma unroll
      for (int ni = 0; ni < 4; ni++) {
        bf16x8 vb = ld8(&Vt[t & 1][(ni * 16 + llo) * 64 + (koff ^ sw)]);
        oacc[0][ni] = MFMA(pa0, vb, oacc[0][ni]);
        oacc[1][ni] = MFMA(pa1, vb, oacc[1][ni]);
      }
    }

    if (t < 15) {
      if (t + 2 < 16) {
        asm volatile("s_waitcnt vmcnt(2)" ::: "memory");
      } else {
        asm volatile("s_waitcnt vmcnt(0)" ::: "memory");
      }
      writeV((t + 1) & 1, nv0, nv1);
      v0 = nv0; v1 = nv1;
      asm volatile("s_waitcnt lgkmcnt(0)" ::: "memory");
      __builtin_amdgcn_s_barrier();
      __builtin_amdgcn_sched_barrier(0);
    }
  }

  float rl[2][4];
#pragma unroll
  for (int mi = 0; mi < 2; mi++) {
    psum[mi] += __shfl_xor(psum[mi], 16);
    psum[mi] += __shfl_xor(psum[mi], 32);
#pragma unroll
    for (int r = 0; r < 4; r++) rl[mi][r] = 1.0f / __shfl(psum[mi], lhi * 4 + r);
  }

#pragma unroll
  for (int mi = 0; mi < 2; mi++)
#pragma unroll
    for (int ni = 0; ni < 4; ni++)
#pragma unroll
      for (int r = 0; r < 4; r++) {
        const size_t row = rowb + wq0 + mi * 16 + lhi * 4 + r;
        outp[row * DIMN + h * HD + ni * 16 + llo] = f2bf(oacc[mi][ni][r] * rl[mi][r]);
      }
}

extern "C" void kernel_launch(void* const* d_in, const int* in_sizes, int n_in,
                              void* d_out, int out_size, void* d_ws, size_t ws_size,
                              hipStream_t stream) {
  const float* x = (const float*)d_in[0];
  const float* Wqkv = (const float*)d_in[1];
  const float* bqkv = (const float*)d_in[2];
  const float* Wproj = (const float*)d_in[3];
  const float* bproj = (const float*)d_in[4];
  const float* g1 = (const float*)d_in[5];
  const float* b1 = (const float*)d_in[6];
  const float* g2 = (const float*)d_in[7];
  const float* b2 = (const float*)d_in[8];
  const float* W1 = (const float*)d_in[9];
  const float* bf1 = (const float*)d_in[10];
  const float* W2 = (const float*)d_in[11];
  const float* bf2 = (const float*)d_in[12];
  float* outp = (float*)d_out;

  char* p = (char*)d_ws;
  u16* WqkvT = (u16*)p; p += (size_t)QKVN * DIMN * 2;
  u16* WprojT = (u16*)p; p += (size_t)DIMN * DIMN * 2;
  u16* W1T = (u16*)p; p += (size_t)HID * DIMN * 2;
  u16* W2T = (u16*)p; p += (size_t)DIMN * HID * 2;
  u16* bufX = (u16*)p; p += (size_t)BNROWS * DIMN * 2;  // h1 / attn_out / h2
  u16* big = (u16*)p; p += (size_t)BNROWS * HID * 2;    // qkv then ff1

  twb_k<<<dim3(QKVN / 32, DIMN / 32), 256, 0, stream>>>(Wqkv, WqkvT, DIMN, QKVN);
  twb_k<<<dim3(DIMN / 32, DIMN / 32), 256, 0, stream>>>(Wproj, WprojT, DIMN, DIMN);
  twb_k<<<dim3(HID / 32, DIMN / 32), 256, 0, stream>>>(W1, W1T, DIMN, HID);
  twb_k<<<dim3(DIMN / 32, HID / 32), 256, 0, stream>>>(W2, W2T, HID, DIMN);

  ln_k<<<BNROWS / 4, 256, 0, stream>>>(x, g1, b1, bufX);
  // QKV GEMM -> big (bf16), 256x256 tile
  gemm256_k<1, 0, 0><<<dim3(64, QKVN / 256), 512, 0, stream>>>(bufX, WqkvT, bqkv, nullptr,
                                                               big, QKVN, DIMN);
  // attention -> bufX (bf16)
  attn_k<<<1536, 256, 0, stream>>>(big, bufX);
  // proj GEMM + residual(x) -> d_out (fp32), 256x128 tile
  gemmP_k<0, 0, 1><<<dim3(64, DIMN / 128), 256, 0, stream>>>(bufX, WprojT, bproj, x, outp,
                                                             DIMN, DIMN);
  ln_k<<<BNROWS / 4, 256, 0, stream>>>(outp, g2, b2, bufX);
  // FF1 (relu) -> big (bf16), 256x256 tile
  gemm256_k<1, 1, 0><<<dim3(64, HID / 256), 512, 0, stream>>>(bufX, W1T, bf1, nullptr, big,
                                                              HID, DIMN);
  // FF2 + residual(d_out) -> d_out (fp32, in place), 256x128 tile
  gemmP_k<0, 0, 1><<<dim3(64, DIMN / 128), 256, 0, stream>>>(big, W2T, bf2, outp, outp,
                                                             DIMN, HID);
}